// Round 3
// baseline (665.601 us; speedup 1.0000x reference)
//
#include <hip/hip_runtime.h>

#define AS1 __attribute__((address_space(1)))
#define AS3 __attribute__((address_space(3)))

typedef __attribute__((ext_vector_type(8))) short bf16x8;
typedef __attribute__((ext_vector_type(4))) float f32x4;

union bf8u { bf16x8 v; unsigned u[4]; };

__device__ __forceinline__ unsigned short f2bf(float f) {
    union { float f; unsigned u; } v; v.f = f;
    unsigned r = v.u + 0x7FFFu + ((v.u >> 16) & 1u);
    return (unsigned short)(r >> 16);
}
__device__ __forceinline__ float bf2f(unsigned short b) {
    union { unsigned u; float f; } v; v.u = (unsigned)b << 16;
    return v.f;
}

__device__ __forceinline__ void gload16(const void* g, void* l) {
    __builtin_amdgcn_global_load_lds((const AS1 unsigned int*)g, (AS3 unsigned int*)l, 16, 0, 0);
}

// ---------- tiled transpose + convert: dst[c*ld_dst + r] = bf16(src[r*ld_src + c]) ----------
__global__ __launch_bounds__(256) void k_transpose_cvt(const float* __restrict__ src,
                                                       unsigned short* __restrict__ dst,
                                                       int ld_src, int ld_dst,
                                                       long zs_src, long zs_dst) {
    __shared__ float tile[32][33];
    long sb = (long)blockIdx.z * zs_src;
    long db = (long)blockIdx.z * zs_dst;
    int c0 = blockIdx.x * 32, r0 = blockIdx.y * 32;
    int tx = threadIdx.x, ty = threadIdx.y;
#pragma unroll
    for (int i = 0; i < 4; i++)
        tile[ty + i * 8][tx] = src[sb + (long)(r0 + ty + i * 8) * ld_src + c0 + tx];
    __syncthreads();
#pragma unroll
    for (int i = 0; i < 4; i++)
        dst[db + (long)(c0 + ty + i * 8) * ld_dst + r0 + tx] = f2bf(tile[tx][ty + i * 8]);
}

// ---------- split-A GEMM: C = A(f32, MxK) * Bt(bf16, NxK)^T, f32 out ----------
// A decomposed in-kernel to bf16 hi+lo, two MFMA passes -> ~2^-18 A-side error.
__global__ __launch_bounds__(256) void k_gemm_a32(const float* __restrict__ A,
                                                  const unsigned short* __restrict__ Bt,
                                                  float* __restrict__ C,
                                                  int M, int N, int K) {
    __shared__ unsigned short Ash[128 * 64];
    __shared__ unsigned short Asl[128 * 64];
    __shared__ unsigned short Bs[128 * 64];
    int tid = threadIdx.x;
    int lane = tid & 63, wid = tid >> 6;
    int g = lane >> 4, fr = lane & 15;
    int rowA0 = blockIdx.y * 128;
    int colB0 = blockIdx.x * 128;

    f32x4 zero = {0.f, 0.f, 0.f, 0.f};
    f32x4 acc[4][4];
#pragma unroll
    for (int mi = 0; mi < 4; mi++)
#pragma unroll
        for (int ni = 0; ni < 4; ni++) acc[mi][ni] = zero;

    const unsigned short* bg[4];
    const float* ag[4];
    int dstA[4];
#pragma unroll
    for (int j = 0; j < 4; j++) {
        int id = j * 256 + tid;
        int r = id >> 3;
        int cb = (id & 7) ^ (r & 7);            // B: pre-swizzled global source chunk
        bg[j] = Bt + (size_t)(colB0 + r) * K + cb * 8;
        int c8 = id & 7;                        // A: linear global, swizzled LDS dest
        ag[j] = A + (size_t)(rowA0 + r) * K + c8 * 8;
        dstA[j] = (r * 8 + (c8 ^ (r & 7))) * 8;
    }

    int nK = K >> 6;
    for (int kt = 0; kt < nK; kt++) {
#pragma unroll
        for (int j = 0; j < 4; j++) {
            int id = j * 256 + tid;
            gload16(bg[j], Bs + id * 8);
            bg[j] += 64;
        }
#pragma unroll
        for (int j = 0; j < 4; j++) {
            float4 v0 = *(const float4*)(ag[j]);
            float4 v1 = *(const float4*)(ag[j] + 4);
            ag[j] += 64;
            float xv[8] = {v0.x, v0.y, v0.z, v0.w, v1.x, v1.y, v1.z, v1.w};
            bf8u hi, lo;
#pragma unroll
            for (int e = 0; e < 4; e++) {
                unsigned short h0 = f2bf(xv[2 * e]), h1 = f2bf(xv[2 * e + 1]);
                unsigned short l0 = f2bf(xv[2 * e] - bf2f(h0));
                unsigned short l1 = f2bf(xv[2 * e + 1] - bf2f(h1));
                hi.u[e] = ((unsigned)h1 << 16) | h0;
                lo.u[e] = ((unsigned)l1 << 16) | l0;
            }
            *(bf16x8*)(Ash + dstA[j]) = hi.v;
            *(bf16x8*)(Asl + dstA[j]) = lo.v;
        }
        __syncthreads();
#pragma unroll
        for (int kk = 0; kk < 2; kk++) {
            bf16x8 afh[4], afl[4], bfr[4];
#pragma unroll
            for (int mi = 0; mi < 4; mi++) {
                int r = (wid >> 1) * 64 + mi * 16 + fr;
                int off = r * 64 + ((((kk << 2) + g) ^ (r & 7)) << 3);
                afh[mi] = *(const bf16x8*)(Ash + off);
                afl[mi] = *(const bf16x8*)(Asl + off);
            }
#pragma unroll
            for (int ni = 0; ni < 4; ni++) {
                int r = (wid & 1) * 64 + ni * 16 + fr;
                bfr[ni] = *(const bf16x8*)(Bs + r * 64 + ((((kk << 2) + g) ^ (r & 7)) << 3));
            }
#pragma unroll
            for (int mi = 0; mi < 4; mi++)
#pragma unroll
                for (int ni = 0; ni < 4; ni++) {
                    acc[mi][ni] = __builtin_amdgcn_mfma_f32_16x16x32_bf16(afh[mi], bfr[ni], acc[mi][ni], 0, 0, 0);
                    acc[mi][ni] = __builtin_amdgcn_mfma_f32_16x16x32_bf16(afl[mi], bfr[ni], acc[mi][ni], 0, 0, 0);
                }
        }
        __syncthreads();
    }

#pragma unroll
    for (int mi = 0; mi < 4; mi++) {
        int row = rowA0 + (wid >> 1) * 64 + mi * 16 + g * 4;
#pragma unroll
        for (int ni = 0; ni < 4; ni++) {
            int col = colB0 + (wid & 1) * 64 + ni * 16 + fr;
#pragma unroll
            for (int r = 0; r < 4; r++)
                C[(size_t)(row + r) * N + col] = acc[mi][ni][r];
        }
    }
}

// ---------- bf16 GEMM (for out-proj): C = A(bf16) * Bt(bf16)^T ----------
__global__ __launch_bounds__(256) void k_gemm_bt(const unsigned short* __restrict__ A,
                                                 const unsigned short* __restrict__ Bt,
                                                 float* __restrict__ C,
                                                 int M, int N, int K) {
    __shared__ unsigned short As[128 * 64];
    __shared__ unsigned short Bs[128 * 64];
    int tid = threadIdx.x;
    int lane = tid & 63, wid = tid >> 6;
    int g = lane >> 4, fr = lane & 15;
    int rowA0 = blockIdx.y * 128;
    int colB0 = blockIdx.x * 128;

    f32x4 zero = {0.f, 0.f, 0.f, 0.f};
    f32x4 acc[4][4];
#pragma unroll
    for (int mi = 0; mi < 4; mi++)
#pragma unroll
        for (int ni = 0; ni < 4; ni++) acc[mi][ni] = zero;

    const unsigned short* ag[4];
    const unsigned short* bg[4];
#pragma unroll
    for (int j = 0; j < 4; j++) {
        int id = j * 256 + tid;
        int r = id >> 3;
        int c = (id & 7) ^ (r & 7);
        ag[j] = A + (size_t)(rowA0 + r) * K + c * 8;
        bg[j] = Bt + (size_t)(colB0 + r) * K + c * 8;
    }

    int nK = K >> 6;
    for (int kt = 0; kt < nK; kt++) {
#pragma unroll
        for (int j = 0; j < 4; j++) {
            int id = j * 256 + tid;
            gload16(ag[j], As + id * 8);
            gload16(bg[j], Bs + id * 8);
            ag[j] += 64; bg[j] += 64;
        }
        __syncthreads();
#pragma unroll
        for (int kk = 0; kk < 2; kk++) {
            bf16x8 af[4], bfr[4];
#pragma unroll
            for (int mi = 0; mi < 4; mi++) {
                int r = (wid >> 1) * 64 + mi * 16 + fr;
                af[mi] = *(const bf16x8*)(As + r * 64 + ((((kk << 2) + g) ^ (r & 7)) << 3));
            }
#pragma unroll
            for (int ni = 0; ni < 4; ni++) {
                int r = (wid & 1) * 64 + ni * 16 + fr;
                bfr[ni] = *(const bf16x8*)(Bs + r * 64 + ((((kk << 2) + g) ^ (r & 7)) << 3));
            }
#pragma unroll
            for (int mi = 0; mi < 4; mi++)
#pragma unroll
                for (int ni = 0; ni < 4; ni++)
                    acc[mi][ni] = __builtin_amdgcn_mfma_f32_16x16x32_bf16(af[mi], bfr[ni], acc[mi][ni], 0, 0, 0);
        }
        __syncthreads();
    }

#pragma unroll
    for (int mi = 0; mi < 4; mi++) {
        int row = rowA0 + (wid >> 1) * 64 + mi * 16 + g * 4;
#pragma unroll
        for (int ni = 0; ni < 4; ni++) {
            int col = colB0 + (wid & 1) * 64 + ni * 16 + fr;
#pragma unroll
            for (int r = 0; r < 4; r++)
                C[(size_t)(row + r) * N + col] = acc[mi][ni][r];
        }
    }
}

// ---------- RMS/L2 norm + partial RoPE; hi/lo split outputs ----------
// grid 65536 = bt(4096) x slot(16). q: packed u32 (hi|lo) IN PLACE over qkv.
// k: planar Khi/Klo head-major. v: normalized f32 in place.
__global__ __launch_bounds__(256) void k_norm_rope(float* __restrict__ qkv,
                                                   const float* __restrict__ q_scale,
                                                   const float* __restrict__ k_scale,
                                                   unsigned short* __restrict__ Khi,
                                                   unsigned short* __restrict__ Klo) {
    __shared__ float Y[256];
    __shared__ float red[4];
    int blk = blockIdx.x;
    int bt = blk >> 4, slot = blk & 15;
    int b = bt >> 11, t = bt & 2047;
    int h = threadIdx.x;
    int lane = h & 63, wid = h >> 6;

    float x = qkv[(size_t)bt * 4096 + slot * 256 + h];
    float v = x * x;
#pragma unroll
    for (int m = 1; m < 64; m <<= 1) v += __shfl_xor(v, m);
    if (lane == 0) red[wid] = v;
    __syncthreads();
    float ss = red[0] + red[1] + red[2] + red[3];

    float y;
    if (slot < 12) {
        float fac = rsqrtf(ss * (1.0f / 256.0f) + 1e-6f);
        const float* sc = (slot < 8) ? q_scale : k_scale;
        y = x * fac * (1.0f + sc[h]);
    } else {
        float fac = rsqrtf(ss + 1e-6f);
        y = x * fac;
    }
    Y[h] = y;
    __syncthreads();

    if (slot < 12) {
        float out;
        int hm = h & 127;
        if (hm < 64) {
            float inv = exp2f(-(float)hm * 0.10381025296522993f); // log2(10000)/128
            float fr = (float)t * inv;
            float s = sinf(fr), c = cosf(fr);
            float y1 = Y[hm], y2 = Y[128 + hm];
            out = (h < 128) ? (y1 * c - y2 * s) : (y2 * c + y1 * s);
        } else {
            out = y;
        }
        unsigned short hb = f2bf(out);
        unsigned short lb = f2bf(out - bf2f(hb));
        if (slot < 8) {
            ((unsigned*)qkv)[(size_t)bt * 4096 + slot * 256 + h] = ((unsigned)hb << 16) | lb;
        } else {
            size_t idx = ((size_t)(b * 4 + (slot - 8)) * 2048 + t) * 256 + h;
            Khi[idx] = hb; Klo[idx] = lb;
        }
    } else {
        qkv[(size_t)bt * 4096 + slot * 256 + h] = y;
    }
}

// ---------- causal flash attention, softcap, hi/lo QK^T (3-pass) ----------
// grid (S/64=32, B*NQ=16), 256 thr = 4 waves, 16 q-rows/wave, KV tile = 32.
__global__ __launch_bounds__(256) void k_attn(const unsigned* __restrict__ Qp,
                                              const unsigned short* __restrict__ Khi,
                                              const unsigned short* __restrict__ Klo,
                                              const unsigned short* __restrict__ Vt,
                                              unsigned short* __restrict__ attn) {
    __shared__ unsigned short Ksh[32 * 256];  // K hi [key][d], chunk ^= (key&7)
    __shared__ unsigned short Ksl[32 * 256];  // K lo
    __shared__ unsigned short Vs[256 * 32];   // [d][key], chunk ^= (d&3)
    __shared__ unsigned short Ps[4][16 * 32]; // per-wave P, chunk ^= (q&3)
    int qt = blockIdx.x * 64;
    int bn = blockIdx.y;
    int b = bn >> 3, n = bn & 7, kv = n >> 1;
    int tid = threadIdx.x, lane = tid & 63, wid = tid >> 6;
    int g = lane >> 4, fr = lane & 15;
    const unsigned short* Kh = Khi + (size_t)(b * 4 + kv) * 2048 * 256;
    const unsigned short* Kl = Klo + (size_t)(b * 4 + kv) * 2048 * 256;
    const unsigned short* Vh = Vt + (size_t)(b * 4 + kv) * 256 * 2048;
    int q0 = qt + wid * 16;

    // Q: packed u32 (hi|lo) in qkv layout [b][t][n*256+h]
    const unsigned* qrow = Qp + (size_t)(b * 2048 + q0 + fr) * 4096 + n * 256;
    bf16x8 aqh[8], aql[8];
#pragma unroll
    for (int kk = 0; kk < 8; kk++) {
        uint4 e0 = *(const uint4*)(qrow + kk * 32 + g * 8);
        uint4 e1 = *(const uint4*)(qrow + kk * 32 + g * 8 + 4);
        bf8u hi, lo;
        hi.u[0] = __builtin_amdgcn_perm(e0.y, e0.x, 0x07060302);
        lo.u[0] = __builtin_amdgcn_perm(e0.y, e0.x, 0x05040100);
        hi.u[1] = __builtin_amdgcn_perm(e0.w, e0.z, 0x07060302);
        lo.u[1] = __builtin_amdgcn_perm(e0.w, e0.z, 0x05040100);
        hi.u[2] = __builtin_amdgcn_perm(e1.y, e1.x, 0x07060302);
        lo.u[2] = __builtin_amdgcn_perm(e1.y, e1.x, 0x05040100);
        hi.u[3] = __builtin_amdgcn_perm(e1.w, e1.z, 0x07060302);
        lo.u[3] = __builtin_amdgcn_perm(e1.w, e1.z, 0x05040100);
        aqh[kk] = hi.v; aql[kk] = lo.v;
    }

    f32x4 zero = {0.f, 0.f, 0.f, 0.f};
    f32x4 o[16];
#pragma unroll
    for (int i = 0; i < 16; i++) o[i] = zero;
    float m_run[4] = {-1e30f, -1e30f, -1e30f, -1e30f};
    float l_run[4] = {0.f, 0.f, 0.f, 0.f};

    int nkt = qt / 32 + 2;
    for (int kt = 0; kt < nkt; kt++) {
        int k0 = kt * 32;
#pragma unroll
        for (int j = 0; j < 4; j++) {   // stage K hi+lo tiles
            int id = j * 256 + tid;
            int r = id >> 5, c = (id & 31) ^ (r & 7);
            gload16(Kh + (size_t)(k0 + r) * 256 + c * 8, Ksh + id * 8);
            gload16(Kl + (size_t)(k0 + r) * 256 + c * 8, Ksl + id * 8);
        }
#pragma unroll
        for (int j = 0; j < 4; j++) {   // stage V tile (d-major)
            int id = j * 256 + tid;
            int d = id >> 2, c = (id & 3) ^ (d & 3);
            gload16(Vh + (size_t)d * 2048 + k0 + c * 8, Vs + id * 8);
        }
        __syncthreads();

        // S = Q K^T: Qhi*Khi + Qlo*Khi + Qhi*Klo
        f32x4 sc2[2] = {zero, zero};
#pragma unroll
        for (int kk = 0; kk < 8; kk++) {
#pragma unroll
            for (int ni = 0; ni < 2; ni++) {
                int kr = ni * 16 + fr;
                int off = kr * 256 + ((((kk << 2) + g) ^ (kr & 7)) << 3);
                bf16x8 bkh = *(const bf16x8*)(Ksh + off);
                bf16x8 bkl = *(const bf16x8*)(Ksl + off);
                sc2[ni] = __builtin_amdgcn_mfma_f32_16x16x32_bf16(aqh[kk], bkh, sc2[ni], 0, 0, 0);
                sc2[ni] = __builtin_amdgcn_mfma_f32_16x16x32_bf16(aql[kk], bkh, sc2[ni], 0, 0, 0);
                sc2[ni] = __builtin_amdgcn_mfma_f32_16x16x32_bf16(aqh[kk], bkl, sc2[ni], 0, 0, 0);
            }
        }

        // softcap then causal mask (reference order)
        float p[2][4];
#pragma unroll
        for (int ni = 0; ni < 2; ni++)
#pragma unroll
            for (int r = 0; r < 4; r++) {
                float s = sc2[ni][r];
                s = 50.0f * tanhf(s * 0.02f);
                int key = k0 + ni * 16 + fr;
                int qr = q0 + g * 4 + r;
                if (key > qr) s = -1e9f;
                p[ni][r] = s;
            }

        // online softmax (row = q, spread over 16 lanes)
        float so[4];
#pragma unroll
        for (int r = 0; r < 4; r++) {
            float m = fmaxf(p[0][r], p[1][r]);
#pragma unroll
            for (int sft = 1; sft < 16; sft <<= 1) m = fmaxf(m, __shfl_xor(m, sft));
            float mnew = fmaxf(m_run[r], m);
            so[r] = __expf(m_run[r] - mnew);
            m_run[r] = mnew;
            float p0 = __expf(p[0][r] - mnew); p[0][r] = p0;
            float p1 = __expf(p[1][r] - mnew); p[1][r] = p1;
            float sum = p0 + p1;
#pragma unroll
            for (int sft = 1; sft < 16; sft <<= 1) sum += __shfl_xor(sum, sft);
            l_run[r] = l_run[r] * so[r] + sum;
        }

        // P (C-layout) -> per-wave LDS -> A-layout fragments
        unsigned short* Pw = Ps[wid];
#pragma unroll
        for (int ni = 0; ni < 2; ni++)
#pragma unroll
            for (int r = 0; r < 4; r++) {
                int q = g * 4 + r, key = ni * 16 + fr;
                Pw[q * 32 + (((key >> 3) ^ (q & 3)) << 3) + (key & 7)] = f2bf(p[ni][r]);
            }
        bf16x8 ap = *(const bf16x8*)(Pw + fr * 32 + ((g ^ (fr & 3)) << 3));

        // O = O*scale + P V
#pragma unroll
        for (int nt = 0; nt < 16; nt++) {
            int dr = nt * 16 + fr;
            bf16x8 bv = *(const bf16x8*)(Vs + dr * 32 + ((g ^ (dr & 3)) << 3));
            f32x4 ot = o[nt];
#pragma unroll
            for (int r = 0; r < 4; r++) ot[r] *= so[r];
            o[nt] = __builtin_amdgcn_mfma_f32_16x16x32_bf16(ap, bv, ot, 0, 0, 0);
        }
        __syncthreads();
    }

#pragma unroll
    for (int r = 0; r < 4; r++) l_run[r] = 1.0f / l_run[r];
#pragma unroll
    for (int nt = 0; nt < 16; nt++)
#pragma unroll
        for (int r = 0; r < 4; r++) {
            int qr = q0 + g * 4 + r;
            attn[(size_t)(b * 2048 + qr) * 2048 + n * 256 + nt * 16 + fr] = f2bf(o[nt][r] * l_run[r]);
        }
}

extern "C" void kernel_launch(void* const* d_in, const int* in_sizes, int n_in,
                              void* d_out, int out_size, void* d_ws, size_t ws_size,
                              hipStream_t stream) {
    const float* x       = (const float*)d_in[0];
    // d_in[1] = attention_mask: deterministically causal -> applied analytically
    const float* Wq      = (const float*)d_in[2];
    const float* Wk      = (const float*)d_in[3];
    const float* Wv      = (const float*)d_in[4];
    const float* Wo      = (const float*)d_in[5];
    const float* q_scale = (const float*)d_in[6];
    const float* k_scale = (const float*)d_in[7];
    float* out = (float*)d_out;
    char* ws = (char*)d_ws;

    // workspace layout (peak 104 MB <= proven 109 MB):
    //   [0,16M):   WT (qkv weights B^T bf16) -> after GEMM1 dead -> Khi[0,8M) Klo[8M,16M)
    //              -> after attn dead -> WoT[0,8M)
    //   [16M,80M): qkv f32 4096x4096 (q-cols become packed u32 Q hi|lo in place)
    //   [80M,88M): Vt bf16 (d-major V)
    //   [88M,104M): attnb bf16 4096x2048
    const size_t MB = 1024 * 1024;
    unsigned short* WT    = (unsigned short*)ws;
    unsigned short* Khi   = (unsigned short*)ws;
    unsigned short* Klo   = (unsigned short*)(ws + 8 * MB);
    unsigned short* WoT   = (unsigned short*)ws;
    float*          qkv   = (float*)(ws + 16 * MB);
    unsigned short* Vt    = (unsigned short*)(ws + 80 * MB);
    unsigned short* attnb = (unsigned short*)(ws + 88 * MB);

    dim3 tb(32, 8);
    k_transpose_cvt<<<dim3(8, 64, 8), tb, 0, stream>>>(Wq, WT, 256, 2048, 524288L, 524288L);
    k_transpose_cvt<<<dim3(8, 64, 4), tb, 0, stream>>>(Wk, WT + (size_t)2048 * 2048, 256, 2048, 524288L, 524288L);
    k_transpose_cvt<<<dim3(8, 64, 4), tb, 0, stream>>>(Wv, WT + (size_t)3072 * 2048, 256, 2048, 524288L, 524288L);

    k_gemm_a32<<<dim3(32, 32), dim3(256), 0, stream>>>(x, WT, qkv, 4096, 4096, 2048);
    k_norm_rope<<<dim3(65536), dim3(256), 0, stream>>>(qkv, q_scale, k_scale, Khi, Klo);
    for (int b = 0; b < 2; b++)
        k_transpose_cvt<<<dim3(8, 64, 4), tb, 0, stream>>>(qkv + (size_t)b * 2048 * 4096 + 3072,
                                                           Vt + (size_t)b * 4 * 256 * 2048,
                                                           4096, 2048, 256L, 524288L);
    k_attn<<<dim3(32, 16), dim3(256), 0, stream>>>((const unsigned*)qkv, Khi, Klo, Vt, attnb);

    k_transpose_cvt<<<dim3(64, 64, 1), tb, 0, stream>>>(Wo, WoT, 2048, 2048, 0L, 0L);
    k_gemm_bt<<<dim3(16, 32), dim3(256), 0, stream>>>(attnb, WoT, out, 4096, 2048, 2048);
}

// Round 4
// 465.915 us; speedup vs baseline: 1.4286x; 1.4286x over previous
//
#include <hip/hip_runtime.h>

#define AS1 __attribute__((address_space(1)))
#define AS3 __attribute__((address_space(3)))

typedef __attribute__((ext_vector_type(8))) short bf16x8;
typedef __attribute__((ext_vector_type(4))) float f32x4;

union bf8u { bf16x8 v; unsigned u[4]; };

__device__ __forceinline__ unsigned short f2bf(float f) {
    union { float f; unsigned u; } v; v.f = f;
    unsigned r = v.u + 0x7FFFu + ((v.u >> 16) & 1u);
    return (unsigned short)(r >> 16);
}
__device__ __forceinline__ float bf2f(unsigned short b) {
    union { unsigned u; float f; } v; v.u = (unsigned)b << 16;
    return v.f;
}

__device__ __forceinline__ void gload16(const void* g, void* l) {
    __builtin_amdgcn_global_load_lds((const AS1 unsigned int*)g, (AS3 unsigned int*)l, 16, 0, 0);
}

// ---------- tiled transpose + convert: dst[c*ld_dst + r] = bf16(src[r*ld_src + c]) ----------
__global__ __launch_bounds__(256) void k_transpose_cvt(const float* __restrict__ src,
                                                       unsigned short* __restrict__ dst,
                                                       int ld_src, int ld_dst,
                                                       long zs_src, long zs_dst) {
    __shared__ float tile[32][33];
    long sb = (long)blockIdx.z * zs_src;
    long db = (long)blockIdx.z * zs_dst;
    int c0 = blockIdx.x * 32, r0 = blockIdx.y * 32;
    int tx = threadIdx.x, ty = threadIdx.y;
#pragma unroll
    for (int i = 0; i < 4; i++)
        tile[ty + i * 8][tx] = src[sb + (long)(r0 + ty + i * 8) * ld_src + c0 + tx];
    __syncthreads();
#pragma unroll
    for (int i = 0; i < 4; i++)
        dst[db + (long)(c0 + ty + i * 8) * ld_dst + r0 + tx] = f2bf(tile[tx][ty + i * 8]);
}

// ---------- split-A GEMM: C = A(f32, MxK) * Bt(bf16, NxK)^T, f32 out ----------
// A decomposed in-kernel to bf16 hi+lo, two MFMA passes -> ~2^-18 A-side error.
__global__ __launch_bounds__(256) void k_gemm_a32(const float* __restrict__ A,
                                                  const unsigned short* __restrict__ Bt,
                                                  float* __restrict__ C,
                                                  int M, int N, int K) {
    __shared__ unsigned short Ash[128 * 64];
    __shared__ unsigned short Asl[128 * 64];
    __shared__ unsigned short Bs[128 * 64];
    int tid = threadIdx.x;
    int lane = tid & 63, wid = tid >> 6;
    int g = lane >> 4, fr = lane & 15;
    int rowA0 = blockIdx.y * 128;
    int colB0 = blockIdx.x * 128;

    f32x4 zero = {0.f, 0.f, 0.f, 0.f};
    f32x4 acc[4][4];
#pragma unroll
    for (int mi = 0; mi < 4; mi++)
#pragma unroll
        for (int ni = 0; ni < 4; ni++) acc[mi][ni] = zero;

    const unsigned short* bg[4];
    const float* ag[4];
    int dstA[4];
#pragma unroll
    for (int j = 0; j < 4; j++) {
        int id = j * 256 + tid;
        int r = id >> 3;
        int cb = (id & 7) ^ (r & 7);            // B: pre-swizzled global source chunk
        bg[j] = Bt + (size_t)(colB0 + r) * K + cb * 8;
        int c8 = id & 7;                        // A: linear global, swizzled LDS dest
        ag[j] = A + (size_t)(rowA0 + r) * K + c8 * 8;
        dstA[j] = (r * 8 + (c8 ^ (r & 7))) * 8;
    }

    int nK = K >> 6;
    for (int kt = 0; kt < nK; kt++) {
#pragma unroll
        for (int j = 0; j < 4; j++) {
            int id = j * 256 + tid;
            gload16(bg[j], Bs + id * 8);
            bg[j] += 64;
        }
#pragma unroll
        for (int j = 0; j < 4; j++) {
            float4 v0 = *(const float4*)(ag[j]);
            float4 v1 = *(const float4*)(ag[j] + 4);
            ag[j] += 64;
            float xv[8] = {v0.x, v0.y, v0.z, v0.w, v1.x, v1.y, v1.z, v1.w};
            bf8u hi, lo;
#pragma unroll
            for (int e = 0; e < 4; e++) {
                unsigned short h0 = f2bf(xv[2 * e]), h1 = f2bf(xv[2 * e + 1]);
                unsigned short l0 = f2bf(xv[2 * e] - bf2f(h0));
                unsigned short l1 = f2bf(xv[2 * e + 1] - bf2f(h1));
                hi.u[e] = ((unsigned)h1 << 16) | h0;
                lo.u[e] = ((unsigned)l1 << 16) | l0;
            }
            *(bf16x8*)(Ash + dstA[j]) = hi.v;
            *(bf16x8*)(Asl + dstA[j]) = lo.v;
        }
        __syncthreads();
#pragma unroll
        for (int kk = 0; kk < 2; kk++) {
            bf16x8 afh[4], afl[4], bfr[4];
#pragma unroll
            for (int mi = 0; mi < 4; mi++) {
                int r = (wid >> 1) * 64 + mi * 16 + fr;
                int off = r * 64 + ((((kk << 2) + g) ^ (r & 7)) << 3);
                afh[mi] = *(const bf16x8*)(Ash + off);
                afl[mi] = *(const bf16x8*)(Asl + off);
            }
#pragma unroll
            for (int ni = 0; ni < 4; ni++) {
                int r = (wid & 1) * 64 + ni * 16 + fr;
                bfr[ni] = *(const bf16x8*)(Bs + r * 64 + ((((kk << 2) + g) ^ (r & 7)) << 3));
            }
#pragma unroll
            for (int mi = 0; mi < 4; mi++)
#pragma unroll
                for (int ni = 0; ni < 4; ni++) {
                    acc[mi][ni] = __builtin_amdgcn_mfma_f32_16x16x32_bf16(afh[mi], bfr[ni], acc[mi][ni], 0, 0, 0);
                    acc[mi][ni] = __builtin_amdgcn_mfma_f32_16x16x32_bf16(afl[mi], bfr[ni], acc[mi][ni], 0, 0, 0);
                }
        }
        __syncthreads();
    }

#pragma unroll
    for (int mi = 0; mi < 4; mi++) {
        int row = rowA0 + (wid >> 1) * 64 + mi * 16 + g * 4;
#pragma unroll
        for (int ni = 0; ni < 4; ni++) {
            int col = colB0 + (wid & 1) * 64 + ni * 16 + fr;
#pragma unroll
            for (int r = 0; r < 4; r++)
                C[(size_t)(row + r) * N + col] = acc[mi][ni][r];
        }
    }
}

// ---------- bf16 GEMM (for out-proj): C = A(bf16) * Bt(bf16)^T ----------
__global__ __launch_bounds__(256) void k_gemm_bt(const unsigned short* __restrict__ A,
                                                 const unsigned short* __restrict__ Bt,
                                                 float* __restrict__ C,
                                                 int M, int N, int K) {
    __shared__ unsigned short As[128 * 64];
    __shared__ unsigned short Bs[128 * 64];
    int tid = threadIdx.x;
    int lane = tid & 63, wid = tid >> 6;
    int g = lane >> 4, fr = lane & 15;
    int rowA0 = blockIdx.y * 128;
    int colB0 = blockIdx.x * 128;

    f32x4 zero = {0.f, 0.f, 0.f, 0.f};
    f32x4 acc[4][4];
#pragma unroll
    for (int mi = 0; mi < 4; mi++)
#pragma unroll
        for (int ni = 0; ni < 4; ni++) acc[mi][ni] = zero;

    const unsigned short* ag[4];
    const unsigned short* bg[4];
#pragma unroll
    for (int j = 0; j < 4; j++) {
        int id = j * 256 + tid;
        int r = id >> 3;
        int c = (id & 7) ^ (r & 7);
        ag[j] = A + (size_t)(rowA0 + r) * K + c * 8;
        bg[j] = Bt + (size_t)(colB0 + r) * K + c * 8;
    }

    int nK = K >> 6;
    for (int kt = 0; kt < nK; kt++) {
#pragma unroll
        for (int j = 0; j < 4; j++) {
            int id = j * 256 + tid;
            gload16(ag[j], As + id * 8);
            gload16(bg[j], Bs + id * 8);
            ag[j] += 64; bg[j] += 64;
        }
        __syncthreads();
#pragma unroll
        for (int kk = 0; kk < 2; kk++) {
            bf16x8 af[4], bfr[4];
#pragma unroll
            for (int mi = 0; mi < 4; mi++) {
                int r = (wid >> 1) * 64 + mi * 16 + fr;
                af[mi] = *(const bf16x8*)(As + r * 64 + ((((kk << 2) + g) ^ (r & 7)) << 3));
            }
#pragma unroll
            for (int ni = 0; ni < 4; ni++) {
                int r = (wid & 1) * 64 + ni * 16 + fr;
                bfr[ni] = *(const bf16x8*)(Bs + r * 64 + ((((kk << 2) + g) ^ (r & 7)) << 3));
            }
#pragma unroll
            for (int mi = 0; mi < 4; mi++)
#pragma unroll
                for (int ni = 0; ni < 4; ni++)
                    acc[mi][ni] = __builtin_amdgcn_mfma_f32_16x16x32_bf16(af[mi], bfr[ni], acc[mi][ni], 0, 0, 0);
        }
        __syncthreads();
    }

#pragma unroll
    for (int mi = 0; mi < 4; mi++) {
        int row = rowA0 + (wid >> 1) * 64 + mi * 16 + g * 4;
#pragma unroll
        for (int ni = 0; ni < 4; ni++) {
            int col = colB0 + (wid & 1) * 64 + ni * 16 + fr;
#pragma unroll
            for (int r = 0; r < 4; r++)
                C[(size_t)(row + r) * N + col] = acc[mi][ni][r];
        }
    }
}

// ---------- RMS/L2 norm + partial RoPE; hi/lo split outputs ----------
// grid 65536 = bt(4096) x slot(16). q: packed u32 (hi|lo) IN PLACE over qkv.
// k: planar Khi/Klo head-major. v: normalized f32 in place.
__global__ __launch_bounds__(256) void k_norm_rope(float* __restrict__ qkv,
                                                   const float* __restrict__ q_scale,
                                                   const float* __restrict__ k_scale,
                                                   unsigned short* __restrict__ Khi,
                                                   unsigned short* __restrict__ Klo) {
    __shared__ float Y[256];
    __shared__ float red[4];
    int blk = blockIdx.x;
    int bt = blk >> 4, slot = blk & 15;
    int b = bt >> 11, t = bt & 2047;
    int h = threadIdx.x;
    int lane = h & 63, wid = h >> 6;

    float x = qkv[(size_t)bt * 4096 + slot * 256 + h];
    float v = x * x;
#pragma unroll
    for (int m = 1; m < 64; m <<= 1) v += __shfl_xor(v, m);
    if (lane == 0) red[wid] = v;
    __syncthreads();
    float ss = red[0] + red[1] + red[2] + red[3];

    float y;
    if (slot < 12) {
        float fac = rsqrtf(ss * (1.0f / 256.0f) + 1e-6f);
        const float* sc = (slot < 8) ? q_scale : k_scale;
        y = x * fac * (1.0f + sc[h]);
    } else {
        float fac = rsqrtf(ss + 1e-6f);
        y = x * fac;
    }
    Y[h] = y;
    __syncthreads();

    if (slot < 12) {
        float out;
        int hm = h & 127;
        if (hm < 64) {
            float inv = exp2f(-(float)hm * 0.10381025296522993f); // log2(10000)/128
            float fr = (float)t * inv;
            float s = sinf(fr), c = cosf(fr);
            float y1 = Y[hm], y2 = Y[128 + hm];
            out = (h < 128) ? (y1 * c - y2 * s) : (y2 * c + y1 * s);
        } else {
            out = y;
        }
        unsigned short hb = f2bf(out);
        unsigned short lb = f2bf(out - bf2f(hb));
        if (slot < 8) {
            ((unsigned*)qkv)[(size_t)bt * 4096 + slot * 256 + h] = ((unsigned)hb << 16) | lb;
        } else {
            size_t idx = ((size_t)(b * 4 + (slot - 8)) * 2048 + t) * 256 + h;
            Khi[idx] = hb; Klo[idx] = lb;
        }
    } else {
        qkv[(size_t)bt * 4096 + slot * 256 + h] = y;
    }
}

// ---------- causal flash attention v2: fold-balanced, XCD-affine, double-buffered ----------
// grid 256 x 512 threads (8 waves). Block id: pair(4b) | npar(1b) | bkv(3b) so id%8 = b*4+kv
// -> each XCD serves ONE kv head (K hi/lo + V = 3MB, L2-resident), 1 block/CU.
// Waves w: tile = {i, 31-i, 32+i, 63-i}[w>>1], 16 q-rows each; sum of tile KV lengths is
// uniform (130 kv-tiles) across blocks; iterations 49..64 (was 2..66).
// 2-phase pipeline: STAGE(next) -> compute(cur) -> one __syncthreads (drains vmcnt).
__global__ __launch_bounds__(512, 2) void k_attn(const unsigned* __restrict__ Qp,
                                                 const unsigned short* __restrict__ Khi,
                                                 const unsigned short* __restrict__ Klo,
                                                 const unsigned short* __restrict__ Vt,
                                                 unsigned short* __restrict__ attn) {
    __shared__ __align__(16) unsigned short Ksh[2][32 * 256];  // K hi [key][d], chunk ^= (key&7)
    __shared__ __align__(16) unsigned short Ksl[2][32 * 256];  // K lo
    __shared__ __align__(16) unsigned short Vs[2][256 * 32];   // [d][key], chunk ^= (d&3)
    __shared__ __align__(16) unsigned short Ps[8][16 * 32];    // per-wave P, chunk ^= (q&3)

    int id = blockIdx.x;
    int pair = id >> 4;
    int low = id & 15;
    int bkv = low & 7;          // = b*4+kv = XCD index
    int npar = low >> 3;
    int b = bkv >> 2, kv = bkv & 3;
    int n = kv * 2 + npar;

    int tid = threadIdx.x, lane = tid & 63, wid = tid >> 6;
    int g = lane >> 4, fr = lane & 15;
    int tsel = wid >> 1;
    int tile = (tsel == 0) ? pair : (tsel == 1) ? 31 - pair : (tsel == 2) ? 32 + pair : 63 - pair;
    int q0 = tile * 32 + (wid & 1) * 16;
    int nkt = 64 - pair;        // = max(tile)+1 over the 4 tiles

    const unsigned short* Kh = Khi + (size_t)bkv * 2048 * 256;
    const unsigned short* Kl = Klo + (size_t)bkv * 2048 * 256;
    const unsigned short* Vh = Vt + (size_t)bkv * 256 * 2048;

    // Q fragments: packed u32 (bf16hi|bf16lo) from qkv layout [b][t][n*256+h]
    const unsigned* qrow = Qp + (size_t)(b * 2048 + q0 + fr) * 4096 + n * 256;
    bf16x8 aqh[8], aql[8];
#pragma unroll
    for (int kk = 0; kk < 8; kk++) {
        uint4 e0 = *(const uint4*)(qrow + kk * 32 + g * 8);
        uint4 e1 = *(const uint4*)(qrow + kk * 32 + g * 8 + 4);
        bf8u hi, lo;
        hi.u[0] = __builtin_amdgcn_perm(e0.y, e0.x, 0x07060302);
        lo.u[0] = __builtin_amdgcn_perm(e0.y, e0.x, 0x05040100);
        hi.u[1] = __builtin_amdgcn_perm(e0.w, e0.z, 0x07060302);
        lo.u[1] = __builtin_amdgcn_perm(e0.w, e0.z, 0x05040100);
        hi.u[2] = __builtin_amdgcn_perm(e1.y, e1.x, 0x07060302);
        lo.u[2] = __builtin_amdgcn_perm(e1.y, e1.x, 0x05040100);
        hi.u[3] = __builtin_amdgcn_perm(e1.w, e1.z, 0x07060302);
        lo.u[3] = __builtin_amdgcn_perm(e1.w, e1.z, 0x05040100);
        aqh[kk] = hi.v; aql[kk] = lo.v;
    }

    f32x4 zero = {0.f, 0.f, 0.f, 0.f};
    f32x4 o[16];
#pragma unroll
    for (int i = 0; i < 16; i++) o[i] = zero;
    float m_run[4] = {-1e30f, -1e30f, -1e30f, -1e30f};
    float l_run[4] = {0.f, 0.f, 0.f, 0.f};

    // stage kv-tile kt2 into buffer bufi: 6 x gload16 per thread (K hi/lo 16KB each, V 16KB)
    auto STAGE = [&](int bufi, int kt2) {
        int k0s = kt2 * 32;
#pragma unroll
        for (int t2 = 0; t2 < 2; t2++) {
            int idx = t2 * 512 + tid;
            int r = idx >> 5, c = (idx & 31) ^ (r & 7);
            gload16(Kh + (size_t)(k0s + r) * 256 + c * 8, &Ksh[bufi][idx * 8]);
            gload16(Kl + (size_t)(k0s + r) * 256 + c * 8, &Ksl[bufi][idx * 8]);
            int d = idx >> 2, cv = (idx & 3) ^ (d & 3);
            gload16(Vh + (size_t)d * 2048 + k0s + cv * 8, &Vs[bufi][idx * 8]);
        }
    };

    STAGE(0, 0);
    __syncthreads();

    for (int kt = 0; kt < nkt; kt++) {
        int cur = kt & 1;
        if (kt + 1 < nkt) STAGE(cur ^ 1, kt + 1);   // prefetch hides under compute

        if (kt <= tile) {
            int k0 = kt * 32;
            const unsigned short* KH = Ksh[cur];
            const unsigned short* KL = Ksl[cur];
            const unsigned short* VC = Vs[cur];

            // S = Q K^T: Qhi*Khi + Qlo*Khi + Qhi*Klo, 6 independent acc chains
            f32x4 s6[3][2];
#pragma unroll
            for (int p2 = 0; p2 < 3; p2++) { s6[p2][0] = zero; s6[p2][1] = zero; }
            __builtin_amdgcn_s_setprio(1);
#pragma unroll
            for (int kk = 0; kk < 8; kk++) {
#pragma unroll
                for (int ni = 0; ni < 2; ni++) {
                    int kr = ni * 16 + fr;
                    int off = kr * 256 + ((((kk << 2) + g) ^ (kr & 7)) << 3);
                    bf16x8 bkh = *(const bf16x8*)(KH + off);
                    bf16x8 bkl = *(const bf16x8*)(KL + off);
                    s6[0][ni] = __builtin_amdgcn_mfma_f32_16x16x32_bf16(aqh[kk], bkh, s6[0][ni], 0, 0, 0);
                    s6[1][ni] = __builtin_amdgcn_mfma_f32_16x16x32_bf16(aql[kk], bkh, s6[1][ni], 0, 0, 0);
                    s6[2][ni] = __builtin_amdgcn_mfma_f32_16x16x32_bf16(aqh[kk], bkl, s6[2][ni], 0, 0, 0);
                }
            }
            __builtin_amdgcn_s_setprio(0);

            // softcap (hand-rolled tanh) then causal mask
            float p[2][4];
#pragma unroll
            for (int ni = 0; ni < 2; ni++)
#pragma unroll
                for (int r = 0; r < 4; r++) {
                    float s = s6[0][ni][r] + s6[1][ni][r] + s6[2][ni][r];
                    float yc = s * 0.02f;
                    float e = __expf(-2.0f * fabsf(yc));
                    float th = (1.0f - e) / (1.0f + e);
                    s = copysignf(50.0f * th, yc);
                    int key = k0 + ni * 16 + fr;
                    int qr = q0 + g * 4 + r;
                    if (key > qr) s = -1e9f;
                    p[ni][r] = s;
                }

            // online softmax (row = q, spread over 16 lanes)
            float so[4];
#pragma unroll
            for (int r = 0; r < 4; r++) {
                float m = fmaxf(p[0][r], p[1][r]);
#pragma unroll
                for (int sft = 1; sft < 16; sft <<= 1) m = fmaxf(m, __shfl_xor(m, sft));
                float mnew = fmaxf(m_run[r], m);
                so[r] = __expf(m_run[r] - mnew);
                m_run[r] = mnew;
                float p0 = __expf(p[0][r] - mnew); p[0][r] = p0;
                float p1 = __expf(p[1][r] - mnew); p[1][r] = p1;
                float sum = p0 + p1;
#pragma unroll
                for (int sft = 1; sft < 16; sft <<= 1) sum += __shfl_xor(sum, sft);
                l_run[r] = l_run[r] * so[r] + sum;
            }

            // P (C-layout) -> per-wave LDS -> A-layout fragments
            unsigned short* Pw = Ps[wid];
#pragma unroll
            for (int ni = 0; ni < 2; ni++)
#pragma unroll
                for (int r = 0; r < 4; r++) {
                    int q = g * 4 + r, key = ni * 16 + fr;
                    Pw[q * 32 + (((key >> 3) ^ (q & 3)) << 3) + (key & 7)] = f2bf(p[ni][r]);
                }
            bf16x8 ap = *(const bf16x8*)(Pw + fr * 32 + ((g ^ (fr & 3)) << 3));

            // O = O*scale + P V
            __builtin_amdgcn_s_setprio(1);
#pragma unroll
            for (int nt = 0; nt < 16; nt++) {
                int dr = nt * 16 + fr;
                bf16x8 bv = *(const bf16x8*)(VC + dr * 32 + ((g ^ (dr & 3)) << 3));
                f32x4 ot = o[nt];
#pragma unroll
                for (int r = 0; r < 4; r++) ot[r] *= so[r];
                o[nt] = __builtin_amdgcn_mfma_f32_16x16x32_bf16(ap, bv, ot, 0, 0, 0);
            }
            __builtin_amdgcn_s_setprio(0);
        }
        __syncthreads();   // drains prefetch vmcnt + LDS; next iter reads other buffer
    }

#pragma unroll
    for (int r = 0; r < 4; r++) l_run[r] = 1.0f / l_run[r];
#pragma unroll
    for (int nt = 0; nt < 16; nt++)
#pragma unroll
        for (int r = 0; r < 4; r++) {
            int qr = q0 + g * 4 + r;
            attn[(size_t)(b * 2048 + qr) * 2048 + n * 256 + nt * 16 + fr] = f2bf(o[nt][r] * l_run[r]);
        }
}

extern "C" void kernel_launch(void* const* d_in, const int* in_sizes, int n_in,
                              void* d_out, int out_size, void* d_ws, size_t ws_size,
                              hipStream_t stream) {
    const float* x       = (const float*)d_in[0];
    // d_in[1] = attention_mask: deterministically causal -> applied analytically
    const float* Wq      = (const float*)d_in[2];
    const float* Wk      = (const float*)d_in[3];
    const float* Wv      = (const float*)d_in[4];
    const float* Wo      = (const float*)d_in[5];
    const float* q_scale = (const float*)d_in[6];
    const float* k_scale = (const float*)d_in[7];
    float* out = (float*)d_out;
    char* ws = (char*)d_ws;

    // workspace layout (peak 104 MB):
    //   [0,16M):   WT (qkv weights B^T bf16) -> after GEMM1 dead -> Khi[0,8M) Klo[8M,16M)
    //              -> after attn dead -> WoT[0,8M)
    //   [16M,80M): qkv f32 4096x4096 (q-cols become packed u32 Q hi|lo in place)
    //   [80M,88M): Vt bf16 (d-major V)
    //   [88M,104M): attnb bf16 4096x2048
    const size_t MB = 1024 * 1024;
    unsigned short* WT    = (unsigned short*)ws;
    unsigned short* Khi   = (unsigned short*)ws;
    unsigned short* Klo   = (unsigned short*)(ws + 8 * MB);
    unsigned short* WoT   = (unsigned short*)ws;
    float*          qkv   = (float*)(ws + 16 * MB);
    unsigned short* Vt    = (unsigned short*)(ws + 80 * MB);
    unsigned short* attnb = (unsigned short*)(ws + 88 * MB);

    dim3 tb(32, 8);
    k_transpose_cvt<<<dim3(8, 64, 8), tb, 0, stream>>>(Wq, WT, 256, 2048, 524288L, 524288L);
    k_transpose_cvt<<<dim3(8, 64, 4), tb, 0, stream>>>(Wk, WT + (size_t)2048 * 2048, 256, 2048, 524288L, 524288L);
    k_transpose_cvt<<<dim3(8, 64, 4), tb, 0, stream>>>(Wv, WT + (size_t)3072 * 2048, 256, 2048, 524288L, 524288L);

    k_gemm_a32<<<dim3(32, 32), dim3(256), 0, stream>>>(x, WT, qkv, 4096, 4096, 2048);
    k_norm_rope<<<dim3(65536), dim3(256), 0, stream>>>(qkv, q_scale, k_scale, Khi, Klo);
    for (int b = 0; b < 2; b++)
        k_transpose_cvt<<<dim3(8, 64, 4), tb, 0, stream>>>(qkv + (size_t)b * 2048 * 4096 + 3072,
                                                           Vt + (size_t)b * 4 * 256 * 2048,
                                                           4096, 2048, 256L, 524288L);
    k_attn<<<dim3(256), dim3(512), 0, stream>>>((const unsigned*)qkv, Khi, Klo, Vt, attnb);

    k_transpose_cvt<<<dim3(64, 64, 1), tb, 0, stream>>>(Wo, WoT, 2048, 2048, 0L, 0L);
    k_gemm_bt<<<dim3(16, 32), dim3(256), 0, stream>>>(attnb, WoT, out, 4096, 2048, 2048);
}

// Round 5
// 298.970 us; speedup vs baseline: 2.2263x; 1.5584x over previous
//
#include <hip/hip_runtime.h>

#define AS1 __attribute__((address_space(1)))
#define AS3 __attribute__((address_space(3)))

typedef __attribute__((ext_vector_type(8))) _Float16 f16x8;
typedef __attribute__((ext_vector_type(4))) float f32x4;

__device__ __forceinline__ unsigned short f2h(float f) {
    union { _Float16 h; unsigned short u; } v; v.h = (_Float16)f; return v.u;
}

__device__ __forceinline__ void gload16(const void* g, void* l) {
    __builtin_amdgcn_global_load_lds((const AS1 unsigned int*)g, (AS3 unsigned int*)l, 16, 0, 0);
}

// ---------- f32 -> fp16 elementwise (x4 vectorized) ----------
__global__ __launch_bounds__(256) void k_cvt(const float* __restrict__ src,
                                             unsigned short* __restrict__ dst, int n4) {
    int i = blockIdx.x * 256 + threadIdx.x;
    if (i >= n4) return;
    float4 v = ((const float4*)src)[i];
    ushort4 o;
    o.x = f2h(v.x); o.y = f2h(v.y); o.z = f2h(v.z); o.w = f2h(v.w);
    ((ushort4*)dst)[i] = o;
}

// ---------- tiled transpose + convert: dst[c*ld_dst + r] = fp16(src[r*ld_src + c]) ----------
__global__ __launch_bounds__(256) void k_transpose_cvt(const float* __restrict__ src,
                                                       unsigned short* __restrict__ dst,
                                                       int ld_src, int ld_dst,
                                                       long zs_src, long zs_dst) {
    __shared__ float tile[32][33];
    long sb = (long)blockIdx.z * zs_src;
    long db = (long)blockIdx.z * zs_dst;
    int c0 = blockIdx.x * 32, r0 = blockIdx.y * 32;
    int tx = threadIdx.x, ty = threadIdx.y;
#pragma unroll
    for (int i = 0; i < 4; i++)
        tile[ty + i * 8][tx] = src[sb + (long)(r0 + ty + i * 8) * ld_src + c0 + tx];
    __syncthreads();
#pragma unroll
    for (int i = 0; i < 4; i++)
        dst[db + (long)(c0 + ty + i * 8) * ld_dst + r0 + tx] = f2h(tile[tx][ty + i * 8]);
}

// ---------- fp16 GEMM: C = A(MxK) * Bt(NxK)^T, f32 out. 128x128 tile, BK=64 ----------
__global__ __launch_bounds__(256) void k_gemm_f16(const unsigned short* __restrict__ A,
                                                  const unsigned short* __restrict__ Bt,
                                                  float* __restrict__ C,
                                                  int M, int N, int K) {
    __shared__ unsigned short As[128 * 64];
    __shared__ unsigned short Bs[128 * 64];
    int tid = threadIdx.x;
    int lane = tid & 63, wid = tid >> 6;
    int g = lane >> 4, fr = lane & 15;
    int rowA0 = blockIdx.y * 128;
    int colB0 = blockIdx.x * 128;

    f32x4 zero = {0.f, 0.f, 0.f, 0.f};
    f32x4 acc[4][4];
#pragma unroll
    for (int mi = 0; mi < 4; mi++)
#pragma unroll
        for (int ni = 0; ni < 4; ni++) acc[mi][ni] = zero;

    const unsigned short* ag[4];
    const unsigned short* bg[4];
#pragma unroll
    for (int j = 0; j < 4; j++) {
        int id = j * 256 + tid;
        int r = id >> 3;
        int c = (id & 7) ^ (r & 7);   // pre-swizzled global source chunk
        ag[j] = A + (size_t)(rowA0 + r) * K + c * 8;
        bg[j] = Bt + (size_t)(colB0 + r) * K + c * 8;
    }

    int nK = K >> 6;
    for (int kt = 0; kt < nK; kt++) {
#pragma unroll
        for (int j = 0; j < 4; j++) {
            int id = j * 256 + tid;
            gload16(ag[j], As + id * 8);
            gload16(bg[j], Bs + id * 8);
            ag[j] += 64; bg[j] += 64;
        }
        __syncthreads();
#pragma unroll
        for (int kk = 0; kk < 2; kk++) {
            f16x8 af[4], bfr[4];
#pragma unroll
            for (int mi = 0; mi < 4; mi++) {
                int r = (wid >> 1) * 64 + mi * 16 + fr;
                af[mi] = *(const f16x8*)(As + r * 64 + ((((kk << 2) + g) ^ (r & 7)) << 3));
            }
#pragma unroll
            for (int ni = 0; ni < 4; ni++) {
                int r = (wid & 1) * 64 + ni * 16 + fr;
                bfr[ni] = *(const f16x8*)(Bs + r * 64 + ((((kk << 2) + g) ^ (r & 7)) << 3));
            }
#pragma unroll
            for (int mi = 0; mi < 4; mi++)
#pragma unroll
                for (int ni = 0; ni < 4; ni++)
                    acc[mi][ni] = __builtin_amdgcn_mfma_f32_16x16x32_f16(af[mi], bfr[ni], acc[mi][ni], 0, 0, 0);
        }
        __syncthreads();
    }

#pragma unroll
    for (int mi = 0; mi < 4; mi++) {
        int row = rowA0 + (wid >> 1) * 64 + mi * 16 + g * 4;
#pragma unroll
        for (int ni = 0; ni < 4; ni++) {
            int col = colB0 + (wid & 1) * 64 + ni * 16 + fr;
#pragma unroll
            for (int r = 0; r < 4; r++)
                C[(size_t)(row + r) * N + col] = acc[mi][ni][r];
        }
    }
}

// ---------- RMS/L2 norm + partial RoPE; fp16 outputs ----------
// grid 65536 = bt(4096) x slot(16): slots 0-7 q heads, 8-11 k heads, 12-15 v heads.
__global__ __launch_bounds__(256) void k_norm_rope(float* __restrict__ qkv,
                                                   const float* __restrict__ q_scale,
                                                   const float* __restrict__ k_scale,
                                                   unsigned short* __restrict__ Qh,
                                                   unsigned short* __restrict__ Kh) {
    __shared__ float Y[256];
    __shared__ float red[4];
    int blk = blockIdx.x;
    int bt = blk >> 4, slot = blk & 15;
    int b = bt >> 11, t = bt & 2047;
    int h = threadIdx.x;
    int lane = h & 63, wid = h >> 6;

    float x = qkv[(size_t)bt * 4096 + slot * 256 + h];
    float v = x * x;
#pragma unroll
    for (int m = 1; m < 64; m <<= 1) v += __shfl_xor(v, m);
    if (lane == 0) red[wid] = v;
    __syncthreads();
    float ss = red[0] + red[1] + red[2] + red[3];

    float y;
    if (slot < 12) {
        float fac = rsqrtf(ss * (1.0f / 256.0f) + 1e-6f);
        const float* sc = (slot < 8) ? q_scale : k_scale;
        y = x * fac * (1.0f + sc[h]);
    } else {
        float fac = rsqrtf(ss + 1e-6f);
        y = x * fac;
    }
    Y[h] = y;
    __syncthreads();

    if (slot < 12) {
        float out;
        int hm = h & 127;
        if (hm < 64) {
            float inv = exp2f(-(float)hm * 0.10381025296522993f); // log2(10000)/128
            float fr = (float)t * inv;
            float s = sinf(fr), c = cosf(fr);
            float y1 = Y[hm], y2 = Y[128 + hm];
            out = (h < 128) ? (y1 * c - y2 * s) : (y2 * c + y1 * s);
        } else {
            out = y;
        }
        unsigned short hv = f2h(out);
        if (slot < 8)
            Qh[((size_t)(b * 8 + slot) * 2048 + t) * 256 + h] = hv;
        else
            Kh[((size_t)(b * 4 + (slot - 8)) * 2048 + t) * 256 + h] = hv;
    } else {
        qkv[(size_t)bt * 4096 + slot * 256 + h] = y;   // normalized v, f32 in-place
    }
}

// ---------- causal flash attention v3: fp16 1-pass, KVBLK=64, key-split waves ----------
// grid 256 x 512 thr (8 waves). id = pair(4b)|npar(1b)|bkv(3b): id%8 = bkv -> XCD-affine
// (K+V per head = 2MB, L2-resident). Waves: r2=wid&3 picks 16 q-rows, c2=wid>>2 picks
// 32-key half of the 64-key tile; each wave runs its own online softmax over disjoint
// keys, flash-merged once per q-tile via LDS. Block processes q-tiles {pair, 31-pair}
// sequentially: (pair+1) + (32-pair) = 33 iterations, uniform, all waves always active.
__global__ __launch_bounds__(512, 2) void k_attn(const unsigned short* __restrict__ Qhg,
                                                 const unsigned short* __restrict__ Khg,
                                                 const unsigned short* __restrict__ Vtg,
                                                 unsigned short* __restrict__ attn) {
    __shared__ __align__(16) char smem[140288];
    unsigned short* Ks = (unsigned short*)smem;                 // [2][64*256] fp16, chunk^=(key&7)
    unsigned short* Vs = (unsigned short*)(smem + 65536);       // [2][256*64] fp16, chunk^=(d&7)
    unsigned short* Ps = (unsigned short*)(smem + 131072);      // [8][16*32] fp16, chunk^=(q&3)
    float* ML = (float*)(smem + 139264);                        // [2][4][4][4][2] (m,l)
    float* X = (float*)smem;                                    // merge overlay [4][64][68] f32

    int id = blockIdx.x;
    int bkv = id & 7;
    int npar = (id >> 3) & 1;
    int pair = id >> 4;
    int b = bkv >> 2, kv = bkv & 3;
    int n = kv * 2 + npar;
    int bn = b * 8 + n;

    int tid = threadIdx.x, lane = tid & 63, wid = tid >> 6;
    int g = lane >> 4, fr = lane & 15;
    int r2 = wid & 3, c2 = wid >> 2;

    const unsigned short* Kh = Khg + (size_t)bkv * 2048 * 256;
    const unsigned short* Vh = Vtg + (size_t)bkv * 256 * 2048;
    const unsigned short* Qb = Qhg + (size_t)bn * 2048 * 256;

    for (int half = 0; half < 2; half++) {
        int j = half ? 31 - pair : pair;
        int q0 = j * 64 + r2 * 16;

        const unsigned short* qrow = Qb + (size_t)(q0 + fr) * 256;
        f16x8 aq[8];
#pragma unroll
        for (int kk = 0; kk < 8; kk++) aq[kk] = *(const f16x8*)(qrow + kk * 32 + g * 8);

        f32x4 zero4 = {0.f, 0.f, 0.f, 0.f};
        f32x4 o[16];
#pragma unroll
        for (int i2 = 0; i2 < 16; i2++) o[i2] = zero4;
        float m_run[4] = {-1e30f, -1e30f, -1e30f, -1e30f};
        float l_run[4] = {0.f, 0.f, 0.f, 0.f};

        // stage 64-key tile kt2 (K 32KB + V 32KB), 8 gload16/thread, LDS dest linear
        auto STAGE = [&](int bufi, int kt2) {
            int k0s = kt2 * 64;
#pragma unroll
            for (int t2 = 0; t2 < 4; t2++) {
                int c_ = t2 * 512 + tid;
                int r = c_ >> 5, c = (c_ & 31) ^ (r & 7);
                gload16(Kh + ((size_t)(k0s + r) * 256 + c * 8), Ks + bufi * 16384 + c_ * 8);
                int d = c_ >> 3, cv = (c_ & 7) ^ (d & 7);
                gload16(Vh + ((size_t)d * 2048 + k0s + cv * 8), Vs + bufi * 16384 + c_ * 8);
            }
        };

        STAGE(0, 0);
        __syncthreads();

        for (int kt = 0; kt <= j; kt++) {
            int cur = kt & 1;
            if (kt < j) STAGE(cur ^ 1, kt + 1);   // prefetch hides under compute

            const unsigned short* KH = Ks + cur * 16384;
            const unsigned short* VC = Vs + cur * 16384;
            int k0 = kt * 64;

            // S = Q K^T over this wave's 32 keys; 4 independent acc chains
            f32x4 se[2] = {zero4, zero4}, so2[2] = {zero4, zero4};
            __builtin_amdgcn_s_setprio(1);
#pragma unroll
            for (int kk = 0; kk < 8; kk += 2) {
#pragma unroll
                for (int ni = 0; ni < 2; ni++) {
                    int kr = c2 * 32 + ni * 16 + fr;
                    f16x8 bk0 = *(const f16x8*)(KH + kr * 256 + (((kk << 2) + g) ^ (kr & 7)) * 8);
                    f16x8 bk1 = *(const f16x8*)(KH + kr * 256 + ((((kk + 1) << 2) + g) ^ (kr & 7)) * 8);
                    se[ni] = __builtin_amdgcn_mfma_f32_16x16x32_f16(aq[kk], bk0, se[ni], 0, 0, 0);
                    so2[ni] = __builtin_amdgcn_mfma_f32_16x16x32_f16(aq[kk + 1], bk1, so2[ni], 0, 0, 0);
                }
            }
            __builtin_amdgcn_s_setprio(0);

            // softcap 50*tanh(s/50) = 50 - 100/(1+e^{0.04s}), then causal mask
            float p[2][4];
#pragma unroll
            for (int ni = 0; ni < 2; ni++)
#pragma unroll
                for (int r = 0; r < 4; r++) {
                    float s = se[ni][r] + so2[ni][r];
                    float e = __expf(0.04f * s);
                    s = 50.f - 100.f * __builtin_amdgcn_rcpf(1.f + e);
                    int key = k0 + c2 * 32 + ni * 16 + fr;
                    int qr = q0 + g * 4 + r;
                    if (key > qr) s = -1e9f;
                    p[ni][r] = s;
                }

            // online softmax (row = q, spread over 16 lanes)
            float sw[4];
#pragma unroll
            for (int r = 0; r < 4; r++) {
                float m = fmaxf(p[0][r], p[1][r]);
#pragma unroll
                for (int sft = 1; sft < 16; sft <<= 1) m = fmaxf(m, __shfl_xor(m, sft));
                float mnew = fmaxf(m_run[r], m);
                sw[r] = __expf(m_run[r] - mnew);
                m_run[r] = mnew;
                float p0 = __expf(p[0][r] - mnew); p[0][r] = p0;
                float p1 = __expf(p[1][r] - mnew); p[1][r] = p1;
                float sum = p0 + p1;
#pragma unroll
                for (int sft = 1; sft < 16; sft <<= 1) sum += __shfl_xor(sum, sft);
                l_run[r] = l_run[r] * sw[r] + sum;
            }

            // P (C-layout) -> per-wave LDS -> A-layout fragment (k=32 local keys)
            unsigned short* Pw = Ps + wid * 512;
#pragma unroll
            for (int ni = 0; ni < 2; ni++)
#pragma unroll
                for (int r = 0; r < 4; r++) {
                    int q = g * 4 + r, kl = ni * 16 + fr;
                    Pw[q * 32 + (((kl >> 3) ^ (q & 3)) << 3) + (kl & 7)] = f2h(p[ni][r]);
                }
            f16x8 ap = *(const f16x8*)(Pw + fr * 32 + ((g ^ (fr & 3)) << 3));

            // O = O*scale + P V (this wave's 32-key slice of V)
            __builtin_amdgcn_s_setprio(1);
#pragma unroll
            for (int nt = 0; nt < 16; nt++) {
                int dr = nt * 16 + fr;
                f16x8 bv = *(const f16x8*)(VC + dr * 64 + ((((c2 << 2) + g) ^ (dr & 7)) << 3));
                f32x4 ot = o[nt];
#pragma unroll
                for (int r = 0; r < 4; r++) ot[r] *= sw[r];
                o[nt] = __builtin_amdgcn_mfma_f32_16x16x32_f16(ap, bv, ot, 0, 0, 0);
            }
            __builtin_amdgcn_s_setprio(0);
            __syncthreads();   // drains prefetch vmcnt; next iter reads other buffer
        }

        // flash-merge the two key-half waves (c2=0/1) per rowgroup, write output
        int mlbase = ((c2 * 4 + r2) * 4 + g) * 4;
        if (fr == 0) {
#pragma unroll
            for (int r = 0; r < 4; r++) {
                ML[(mlbase + r) * 2] = m_run[r];
                ML[(mlbase + r) * 2 + 1] = l_run[r];
            }
        }
        __syncthreads();
        int plbase = (((1 - c2) * 4 + r2) * 4 + g) * 4;
        float wS[4], linv[4];
#pragma unroll
        for (int r = 0; r < 4; r++) {
            float mp = ML[(plbase + r) * 2], lp = ML[(plbase + r) * 2 + 1];
            float ms = fmaxf(m_run[r], mp);
            wS[r] = __expf(m_run[r] - ms);
            float wp = __expf(mp - ms);
            linv[r] = __builtin_amdgcn_rcpf(l_run[r] * wS[r] + lp * wp);
        }
        float* Xl = X + (r2 * 64 + lane) * 68;
        if (c2 == 1) {
#pragma unroll
            for (int nt = 0; nt < 16; nt++)
#pragma unroll
                for (int r = 0; r < 4; r++) Xl[nt * 4 + r] = o[nt][r] * wS[r];
        }
        __syncthreads();
        if (c2 == 0) {
#pragma unroll
            for (int nt = 0; nt < 16; nt++)
#pragma unroll
                for (int r = 0; r < 4; r++) {
                    float val = (o[nt][r] * wS[r] + Xl[nt * 4 + r]) * linv[r];
                    int qr = q0 + g * 4 + r;
                    attn[(size_t)(b * 2048 + qr) * 2048 + n * 256 + nt * 16 + fr] = f2h(val);
                }
        }
        __syncthreads();   // protect LDS before next q-tile's STAGE
    }
}

extern "C" void kernel_launch(void* const* d_in, const int* in_sizes, int n_in,
                              void* d_out, int out_size, void* d_ws, size_t ws_size,
                              hipStream_t stream) {
    const float* x       = (const float*)d_in[0];
    // d_in[1] = attention_mask: deterministically causal -> applied analytically
    const float* Wq      = (const float*)d_in[2];
    const float* Wk      = (const float*)d_in[3];
    const float* Wv      = (const float*)d_in[4];
    const float* Wo      = (const float*)d_in[5];
    const float* q_scale = (const float*)d_in[6];
    const float* k_scale = (const float*)d_in[7];
    float* out = (float*)d_out;
    char* ws = (char*)d_ws;

    // workspace (peak 104 MB):
    //   [0,16M):   xh fp16 (x converted) -> dead after GEMM1 -> Qh fp16 [16][2048][256]
    //   [16M,32M): WT fp16 (qkv weights B^T) -> dead after GEMM1 -> Kh[16,24M) Vt[24,32M)
    //   [32M,40M): WoT fp16
    //   [40M,104M): qkv f32 4096x4096 -> dead after V-transpose -> attnb fp16 [40,56M)
    const size_t MB = 1024 * 1024;
    unsigned short* xh    = (unsigned short*)ws;
    unsigned short* Qh    = (unsigned short*)ws;
    unsigned short* WT    = (unsigned short*)(ws + 16 * MB);
    unsigned short* Kh    = (unsigned short*)(ws + 16 * MB);
    unsigned short* Vt    = (unsigned short*)(ws + 24 * MB);
    unsigned short* WoT   = (unsigned short*)(ws + 32 * MB);
    float*          qkv   = (float*)(ws + 40 * MB);
    unsigned short* attnb = (unsigned short*)(ws + 40 * MB);

    dim3 tb(32, 8);
    k_cvt<<<dim3(8192), dim3(256), 0, stream>>>(x, xh, 2097152);
    k_transpose_cvt<<<dim3(8, 64, 8), tb, 0, stream>>>(Wq, WT, 256, 2048, 524288L, 524288L);
    k_transpose_cvt<<<dim3(8, 64, 4), tb, 0, stream>>>(Wk, WT + (size_t)2048 * 2048, 256, 2048, 524288L, 524288L);
    k_transpose_cvt<<<dim3(8, 64, 4), tb, 0, stream>>>(Wv, WT + (size_t)3072 * 2048, 256, 2048, 524288L, 524288L);

    k_gemm_f16<<<dim3(32, 32), dim3(256), 0, stream>>>(xh, WT, qkv, 4096, 4096, 2048);
    k_norm_rope<<<dim3(65536), dim3(256), 0, stream>>>(qkv, q_scale, k_scale, Qh, Kh);
    for (int b = 0; b < 2; b++)
        k_transpose_cvt<<<dim3(8, 64, 4), tb, 0, stream>>>(qkv + (size_t)b * 2048 * 4096 + 3072,
                                                           Vt + (size_t)b * 4 * 256 * 2048,
                                                           4096, 2048, 256L, 524288L);
    k_attn<<<dim3(256), dim3(512), 0, stream>>>(Qh, Kh, Vt, attnb);

    k_transpose_cvt<<<dim3(64, 64, 1), tb, 0, stream>>>(Wo, WoT, 2048, 2048, 0L, 0L);
    k_gemm_f16<<<dim3(16, 32), dim3(256), 0, stream>>>(attnb, WoT, out, 4096, 2048, 2048);
}

// Round 6
// 275.367 us; speedup vs baseline: 2.4171x; 1.0857x over previous
//
#include <hip/hip_runtime.h>

#define AS1 __attribute__((address_space(1)))
#define AS3 __attribute__((address_space(3)))

typedef __attribute__((ext_vector_type(8))) _Float16 f16x8;
typedef __attribute__((ext_vector_type(4))) float f32x4;

__device__ __forceinline__ unsigned short f2h(float f) {
    union { _Float16 h; unsigned short u; } v; v.h = (_Float16)f; return v.u;
}

__device__ __forceinline__ void gload16(const void* g, void* l) {
    __builtin_amdgcn_global_load_lds((const AS1 unsigned int*)g, (AS3 unsigned int*)l, 16, 0, 0);
}

#define GBAR() __builtin_amdgcn_s_barrier()
#define VM4()  asm volatile("s_waitcnt vmcnt(4)" ::: "memory")
#define VM0()  asm volatile("s_waitcnt vmcnt(0)" ::: "memory")

// ---------- f32 -> fp16 elementwise (x4 vectorized) ----------
__global__ __launch_bounds__(256) void k_cvt(const float* __restrict__ src,
                                             unsigned short* __restrict__ dst, int n4) {
    int i = blockIdx.x * 256 + threadIdx.x;
    if (i >= n4) return;
    float4 v = ((const float4*)src)[i];
    ushort4 o;
    o.x = f2h(v.x); o.y = f2h(v.y); o.z = f2h(v.z); o.w = f2h(v.w);
    ((ushort4*)dst)[i] = o;
}

// ---------- tiled transpose + convert: dst[c*ld_dst + r] = fp16(src[r*ld_src + c]) ----------
__global__ __launch_bounds__(256) void k_transpose_cvt(const float* __restrict__ src,
                                                       unsigned short* __restrict__ dst,
                                                       int ld_src, int ld_dst,
                                                       long zs_src, long zs_dst) {
    __shared__ float tile[32][33];
    long sb = (long)blockIdx.z * zs_src;
    long db = (long)blockIdx.z * zs_dst;
    int c0 = blockIdx.x * 32, r0 = blockIdx.y * 32;
    int tx = threadIdx.x, ty = threadIdx.y;
#pragma unroll
    for (int i = 0; i < 4; i++)
        tile[ty + i * 8][tx] = src[sb + (long)(r0 + ty + i * 8) * ld_src + c0 + tx];
    __syncthreads();
#pragma unroll
    for (int i = 0; i < 4; i++)
        dst[db + (long)(c0 + ty + i * 8) * ld_dst + r0 + tx] = f2h(tile[tx][ty + i * 8]);
}

// ======== 256x256 8-phase fp16 GEMM (T2+T3+T4+T5): C = A(MxK) * Bt(NxK)^T, f32 out ========
// 512 thr = 8 waves (2M x 4N), BK=64, LDS 128KB = [2buf][2half] for A and B.
// A half h = rows {h*64..h*64+63} U {128+h*64..}, LDS pos = blk*64... see stage/read maps.
// Counted vmcnt(4) at phases 4/8 only; per-phase: ds_read / stage-1-half / bar / MFMA / bar.

template<int BUF, int MIH>
__device__ __forceinline__ void rdA(const unsigned short* SA, int wm, int fr, int g,
                                    f16x8 (&af)[4][2]) {
#pragma unroll
    for (int m = 0; m < 4; m++)
#pragma unroll
        for (int kk = 0; kk < 2; kk++) {
            int pos = wm * 64 + m * 16 + fr;
            af[m][kk] = *(const f16x8*)(SA + BUF * 16384 + MIH * 8192 + pos * 64 +
                                        (((kk * 4 + g) ^ (fr & 7)) << 3));
        }
}

template<int BUF, int NIH>
__device__ __forceinline__ void rdB(const unsigned short* SB, int wn, int fr, int g,
                                    f16x8 (&bf)[2][2]) {
#pragma unroll
    for (int ni2 = 0; ni2 < 2; ni2++)
#pragma unroll
        for (int kk = 0; kk < 2; kk++) {
            int pos = wn * 32 + ni2 * 16 + fr;
            bf[ni2][kk] = *(const f16x8*)(SB + BUF * 16384 + NIH * 8192 + pos * 64 +
                                          (((kk * 4 + g) ^ (fr & 7)) << 3));
        }
}

template<int MIH, int NIH>
__device__ __forceinline__ void mm16(f16x8 (&af)[4][2], f16x8 (&bf)[2][2], f32x4 (&acc)[8][4]) {
    __builtin_amdgcn_s_setprio(1);
#pragma unroll
    for (int m = 0; m < 4; m++)
#pragma unroll
        for (int ni2 = 0; ni2 < 2; ni2++)
#pragma unroll
            for (int kk = 0; kk < 2; kk++)
                acc[MIH * 4 + m][NIH * 2 + ni2] = __builtin_amdgcn_mfma_f32_16x16x32_f16(
                    af[m][kk], bf[ni2][kk], acc[MIH * 4 + m][NIH * 2 + ni2], 0, 0, 0);
    __builtin_amdgcn_s_setprio(0);
}

__global__ __launch_bounds__(512, 1) void k_gemm256(const unsigned short* __restrict__ A,
                                                    const unsigned short* __restrict__ Bt,
                                                    float* __restrict__ C,
                                                    int M, int N, int K, int nbx) {
    __shared__ __align__(16) unsigned short sm[65536];   // 128 KB
    unsigned short* SA = sm;            // elem: buf*16384 + h*8192 + pos*64 + e
    unsigned short* SB = sm + 32768;

    int tid = threadIdx.x, lane = tid & 63, wid = tid >> 6;
    int g = lane >> 4, fr = lane & 15;
    int wm = wid >> 2, wn = wid & 3;

    int bid = blockIdx.x;                       // XCD-affine bijective swizzle (nwg%8==0)
    int sid = (bid & 7) * ((int)gridDim.x >> 3) + (bid >> 3);
    int by = sid / nbx, bx = sid % nbx;
    int rowA0 = by * 256, colB0 = bx * 256;

    f32x4 acc[8][4];
#pragma unroll
    for (int mi = 0; mi < 8; mi++)
#pragma unroll
        for (int ni = 0; ni < 4; ni++) acc[mi][ni] = (f32x4){0.f, 0.f, 0.f, 0.f};

    // stage half h of K-tile kt into buffer buf (2 x gload16 per thread = 16KB)
    auto stA = [&](int buf, int h, int kt) {
#pragma unroll
        for (int t = 0; t < 2; t++) {
            int i = t * 512 + tid;
            int pos = i >> 3;
            int grow = rowA0 + ((pos >> 6) << 7) + h * 64 + (pos & 63);
            int cg = (i & 7) ^ (pos & 7);
            gload16(A + (size_t)grow * K + kt * 64 + cg * 8,
                    SA + buf * 16384 + h * 8192 + pos * 64 + (i & 7) * 8);
        }
    };
    auto stB = [&](int buf, int h, int kt) {
#pragma unroll
        for (int t = 0; t < 2; t++) {
            int i = t * 512 + tid;
            int pos = i >> 3;
            int gcol = colB0 + ((pos >> 5) << 6) + h * 32 + (pos & 31);
            int cg = (i & 7) ^ (pos & 7);
            gload16(Bt + (size_t)gcol * K + kt * 64 + cg * 8,
                    SB + buf * 16384 + h * 8192 + pos * 64 + (i & 7) * 8);
        }
    };

    int nT = K >> 6;          // 32 K-tiles, 16 iters x 2 tiles
    // prologue: tile0 full + tile1 {A0,B0}; vmcnt(4) leaves only tile1's halves in flight
    stA(0, 0, 0); stB(0, 0, 0); stA(0, 1, 0); stB(0, 1, 0);
    stA(1, 0, 1); stB(1, 0, 1);
    VM4();
    GBAR();

    f16x8 af[4][2], bf[2][2];
    int nIt = nT >> 1;
    for (int it = 0; it < nIt; it++) {
        int T = it * 2;
        bool s36 = (T + 2 < nT), s78 = (T + 3 < nT);
        // ph1 (buf0: mih0,nih0)  stage A1(T+1)->buf1
        rdA<0, 0>(SA, wm, fr, g, af); rdB<0, 0>(SB, wn, fr, g, bf);
        stA(1, 1, T + 1);
        GBAR(); mm16<0, 0>(af, bf, acc); GBAR();
        // ph2 (0,1)  stage B1(T+1)->buf1
        rdB<0, 1>(SB, wn, fr, g, bf);
        stB(1, 1, T + 1);
        GBAR(); mm16<0, 1>(af, bf, acc); GBAR();
        // ph3 (1,0)  stage A0(T+2)->buf0
        rdA<0, 1>(SA, wm, fr, g, af); rdB<0, 0>(SB, wn, fr, g, bf);
        if (s36) stA(0, 0, T + 2);
        GBAR(); mm16<1, 0>(af, bf, acc); GBAR();
        // ph4 (1,1)  stage B0(T+2)->buf0 ; counted vmcnt
        rdB<0, 1>(SB, wn, fr, g, bf);
        if (s36) { stB(0, 0, T + 2); VM4(); } else { VM0(); }
        GBAR(); mm16<1, 1>(af, bf, acc); GBAR();
        // ph5 (buf1: 0,0)  stage A1(T+2)->buf0
        rdA<1, 0>(SA, wm, fr, g, af); rdB<1, 0>(SB, wn, fr, g, bf);
        if (s36) stA(0, 1, T + 2);
        GBAR(); mm16<0, 0>(af, bf, acc); GBAR();
        // ph6 (0,1)  stage B1(T+2)->buf0
        rdB<1, 1>(SB, wn, fr, g, bf);
        if (s36) stB(0, 1, T + 2);
        GBAR(); mm16<0, 1>(af, bf, acc); GBAR();
        // ph7 (1,0)  stage A0(T+3)->buf1
        rdA<1, 1>(SA, wm, fr, g, af); rdB<1, 0>(SB, wn, fr, g, bf);
        if (s78) stA(1, 0, T + 3);
        GBAR(); mm16<1, 0>(af, bf, acc); GBAR();
        // ph8 (1,1)  stage B0(T+3)->buf1 ; counted vmcnt
        rdB<1, 1>(SB, wn, fr, g, bf);
        if (s78) { stB(1, 0, T + 3); VM4(); } else { VM0(); }
        GBAR(); mm16<1, 1>(af, bf, acc); GBAR();
    }

#pragma unroll
    for (int mi = 0; mi < 8; mi++) {
        int row = rowA0 + wm * 128 + mi * 16 + g * 4;
#pragma unroll
        for (int ni = 0; ni < 4; ni++) {
            int col = colB0 + wn * 64 + ni * 16 + fr;
#pragma unroll
            for (int r = 0; r < 4; r++)
                C[(size_t)(row + r) * N + col] = acc[mi][ni][r];
        }
    }
}

// ---------- fp16 GEMM (out-proj): C = A(MxK) * Bt(NxK)^T, f32 out. 128x128 tile ----------
__global__ __launch_bounds__(256) void k_gemm_f16(const unsigned short* __restrict__ A,
                                                  const unsigned short* __restrict__ Bt,
                                                  float* __restrict__ C,
                                                  int M, int N, int K) {
    __shared__ unsigned short As[128 * 64];
    __shared__ unsigned short Bs[128 * 64];
    int tid = threadIdx.x;
    int lane = tid & 63, wid = tid >> 6;
    int g = lane >> 4, fr = lane & 15;
    int rowA0 = blockIdx.y * 128;
    int colB0 = blockIdx.x * 128;

    f32x4 zero = {0.f, 0.f, 0.f, 0.f};
    f32x4 acc[4][4];
#pragma unroll
    for (int mi = 0; mi < 4; mi++)
#pragma unroll
        for (int ni = 0; ni < 4; ni++) acc[mi][ni] = zero;

    const unsigned short* ag[4];
    const unsigned short* bg[4];
#pragma unroll
    for (int j = 0; j < 4; j++) {
        int id = j * 256 + tid;
        int r = id >> 3;
        int c = (id & 7) ^ (r & 7);
        ag[j] = A + (size_t)(rowA0 + r) * K + c * 8;
        bg[j] = Bt + (size_t)(colB0 + r) * K + c * 8;
    }

    int nK = K >> 6;
    for (int kt = 0; kt < nK; kt++) {
#pragma unroll
        for (int j = 0; j < 4; j++) {
            int id = j * 256 + tid;
            gload16(ag[j], As + id * 8);
            gload16(bg[j], Bs + id * 8);
            ag[j] += 64; bg[j] += 64;
        }
        __syncthreads();
#pragma unroll
        for (int kk = 0; kk < 2; kk++) {
            f16x8 af[4], bfr[4];
#pragma unroll
            for (int mi = 0; mi < 4; mi++) {
                int r = (wid >> 1) * 64 + mi * 16 + fr;
                af[mi] = *(const f16x8*)(As + r * 64 + ((((kk << 2) + g) ^ (r & 7)) << 3));
            }
#pragma unroll
            for (int ni = 0; ni < 4; ni++) {
                int r = (wid & 1) * 64 + ni * 16 + fr;
                bfr[ni] = *(const f16x8*)(Bs + r * 64 + ((((kk << 2) + g) ^ (r & 7)) << 3));
            }
#pragma unroll
            for (int mi = 0; mi < 4; mi++)
#pragma unroll
                for (int ni = 0; ni < 4; ni++)
                    acc[mi][ni] = __builtin_amdgcn_mfma_f32_16x16x32_f16(af[mi], bfr[ni], acc[mi][ni], 0, 0, 0);
        }
        __syncthreads();
    }

#pragma unroll
    for (int mi = 0; mi < 4; mi++) {
        int row = rowA0 + (wid >> 1) * 64 + mi * 16 + g * 4;
#pragma unroll
        for (int ni = 0; ni < 4; ni++) {
            int col = colB0 + (wid & 1) * 64 + ni * 16 + fr;
#pragma unroll
            for (int r = 0; r < 4; r++)
                C[(size_t)(row + r) * N + col] = acc[mi][ni][r];
        }
    }
}

// ---------- RMS/L2 norm + partial RoPE; fp16 outputs ----------
__global__ __launch_bounds__(256) void k_norm_rope(float* __restrict__ qkv,
                                                   const float* __restrict__ q_scale,
                                                   const float* __restrict__ k_scale,
                                                   unsigned short* __restrict__ Qh,
                                                   unsigned short* __restrict__ Kh) {
    __shared__ float Y[256];
    __shared__ float red[4];
    int blk = blockIdx.x;
    int bt = blk >> 4, slot = blk & 15;
    int b = bt >> 11, t = bt & 2047;
    int h = threadIdx.x;
    int lane = h & 63, wid = h >> 6;

    float x = qkv[(size_t)bt * 4096 + slot * 256 + h];
    float v = x * x;
#pragma unroll
    for (int m = 1; m < 64; m <<= 1) v += __shfl_xor(v, m);
    if (lane == 0) red[wid] = v;
    __syncthreads();
    float ss = red[0] + red[1] + red[2] + red[3];

    float y;
    if (slot < 12) {
        float fac = rsqrtf(ss * (1.0f / 256.0f) + 1e-6f);
        const float* sc = (slot < 8) ? q_scale : k_scale;
        y = x * fac * (1.0f + sc[h]);
    } else {
        float fac = rsqrtf(ss + 1e-6f);
        y = x * fac;
    }
    Y[h] = y;
    __syncthreads();

    if (slot < 12) {
        float out;
        int hm = h & 127;
        if (hm < 64) {
            float inv = exp2f(-(float)hm * 0.10381025296522993f); // log2(10000)/128
            float fr = (float)t * inv;
            float s = sinf(fr), c = cosf(fr);
            float y1 = Y[hm], y2 = Y[128 + hm];
            out = (h < 128) ? (y1 * c - y2 * s) : (y2 * c + y1 * s);
        } else {
            out = y;
        }
        unsigned short hv = f2h(out);
        if (slot < 8)
            Qh[((size_t)(b * 8 + slot) * 2048 + t) * 256 + h] = hv;
        else
            Kh[((size_t)(b * 4 + (slot - 8)) * 2048 + t) * 256 + h] = hv;
    } else {
        qkv[(size_t)bt * 4096 + slot * 256 + h] = y;   // normalized v, f32 in-place
    }
}

// ---------- causal flash attention v4: + per-lane l, defer-max (T13) ----------
// grid 256 x 512 thr (8 waves). id = pair(4b)|npar(1b)|bkv(3b): id%8 = bkv -> XCD-affine.
// Waves: r2=wid&3 picks 16 q-rows, c2=wid>>2 picks 32-key half; online softmax per wave,
// flash-merged per q-tile via LDS. q-tiles {pair, 31-pair}: 33 uniform iterations.
__global__ __launch_bounds__(512, 2) void k_attn(const unsigned short* __restrict__ Qhg,
                                                 const unsigned short* __restrict__ Khg,
                                                 const unsigned short* __restrict__ Vtg,
                                                 unsigned short* __restrict__ attn) {
    __shared__ __align__(16) char smem[140288];
    unsigned short* Ks = (unsigned short*)smem;                 // [2][64*256] fp16, chunk^=(key&7)
    unsigned short* Vs = (unsigned short*)(smem + 65536);       // [2][256*64] fp16, chunk^=(d&7)
    unsigned short* Ps = (unsigned short*)(smem + 131072);      // [8][16*32] fp16, chunk^=(q&3)
    float* ML = (float*)(smem + 139264);                        // [2][4][4][4][2] (m,l)
    float* X = (float*)smem;                                    // merge overlay [4][64][68] f32

    int id = blockIdx.x;
    int bkv = id & 7;
    int npar = (id >> 3) & 1;
    int pair = id >> 4;
    int b = bkv >> 2, kv = bkv & 3;
    int n = kv * 2 + npar;
    int bn = b * 8 + n;

    int tid = threadIdx.x, lane = tid & 63, wid = tid >> 6;
    int g = lane >> 4, fr = lane & 15;
    int r2 = wid & 3, c2 = wid >> 2;

    const unsigned short* Kh = Khg + (size_t)bkv * 2048 * 256;
    const unsigned short* Vh = Vtg + (size_t)bkv * 256 * 2048;
    const unsigned short* Qb = Qhg + (size_t)bn * 2048 * 256;

    for (int half = 0; half < 2; half++) {
        int j = half ? 31 - pair : pair;
        int q0 = j * 64 + r2 * 16;

        const unsigned short* qrow = Qb + (size_t)(q0 + fr) * 256;
        f16x8 aq[8];
#pragma unroll
        for (int kk = 0; kk < 8; kk++) aq[kk] = *(const f16x8*)(qrow + kk * 32 + g * 8);

        f32x4 zero4 = {0.f, 0.f, 0.f, 0.f};
        f32x4 o[16];
#pragma unroll
        for (int i2 = 0; i2 < 16; i2++) o[i2] = zero4;
        float m_run[4] = {-1e30f, -1e30f, -1e30f, -1e30f};
        float l_run[4] = {0.f, 0.f, 0.f, 0.f};   // per-lane partial sums (reduced at merge)

        auto STAGE = [&](int bufi, int kt2) {
            int k0s = kt2 * 64;
#pragma unroll
            for (int t2 = 0; t2 < 4; t2++) {
                int c_ = t2 * 512 + tid;
                int r = c_ >> 5, c = (c_ & 31) ^ (r & 7);
                gload16(Kh + ((size_t)(k0s + r) * 256 + c * 8), Ks + bufi * 16384 + c_ * 8);
                int d = c_ >> 3, cv = (c_ & 7) ^ (d & 7);
                gload16(Vh + ((size_t)d * 2048 + k0s + cv * 8), Vs + bufi * 16384 + c_ * 8);
            }
        };

        STAGE(0, 0);
        __syncthreads();

        for (int kt = 0; kt <= j; kt++) {
            int cur = kt & 1;
            if (kt < j) STAGE(cur ^ 1, kt + 1);   // prefetch hides under compute

            const unsigned short* KH = Ks + cur * 16384;
            const unsigned short* VC = Vs + cur * 16384;
            int k0 = kt * 64;

            // S = Q K^T over this wave's 32 keys; 4 independent acc chains
            f32x4 se[2] = {zero4, zero4}, so2[2] = {zero4, zero4};
            __builtin_amdgcn_s_setprio(1);
#pragma unroll
            for (int kk = 0; kk < 8; kk += 2) {
#pragma unroll
                for (int ni = 0; ni < 2; ni++) {
                    int kr = c2 * 32 + ni * 16 + fr;
                    f16x8 bk0 = *(const f16x8*)(KH + kr * 256 + (((kk << 2) + g) ^ (kr & 7)) * 8);
                    f16x8 bk1 = *(const f16x8*)(KH + kr * 256 + ((((kk + 1) << 2) + g) ^ (kr & 7)) * 8);
                    se[ni] = __builtin_amdgcn_mfma_f32_16x16x32_f16(aq[kk], bk0, se[ni], 0, 0, 0);
                    so2[ni] = __builtin_amdgcn_mfma_f32_16x16x32_f16(aq[kk + 1], bk1, so2[ni], 0, 0, 0);
                }
            }
            __builtin_amdgcn_s_setprio(0);

            // softcap 50*tanh(s/50) = 50 - 100/(1+e^{0.04s}), then causal mask
            float p[2][4];
#pragma unroll
            for (int ni = 0; ni < 2; ni++)
#pragma unroll
                for (int r = 0; r < 4; r++) {
                    float s = se[ni][r] + so2[ni][r];
                    float e = __expf(0.04f * s);
                    s = 50.f - 100.f * __builtin_amdgcn_rcpf(1.f + e);
                    int key = k0 + c2 * 32 + ni * 16 + fr;
                    int qr = q0 + g * 4 + r;
                    if (key > qr) s = -1e9f;
                    p[ni][r] = s;
                }

            // online softmax with defer-max (THR=8): row max via 16-lane chain
            float mrow[4];
#pragma unroll
            for (int r = 0; r < 4; r++) {
                float m = fmaxf(p[0][r], p[1][r]);
#pragma unroll
                for (int sft = 1; sft < 16; sft <<= 1) m = fmaxf(m, __shfl_xor(m, sft));
                mrow[r] = m;
            }
            int needs = (mrow[0] > m_run[0] + 8.f) || (mrow[1] > m_run[1] + 8.f) ||
                        (mrow[2] > m_run[2] + 8.f) || (mrow[3] > m_run[3] + 8.f);
            if (__any(needs)) {                    // rescale path (wave-uniform)
                float sw[4];
#pragma unroll
                for (int r = 0; r < 4; r++) {
                    float mnew = fmaxf(m_run[r], mrow[r]);
                    sw[r] = __expf(m_run[r] - mnew);
                    m_run[r] = mnew;
                    l_run[r] *= sw[r];
                }
#pragma unroll
                for (int nt = 0; nt < 16; nt++)
#pragma unroll
                    for (int r = 0; r < 4; r++) o[nt][r] *= sw[r];
            }
#pragma unroll
            for (int r = 0; r < 4; r++) {
                float p0 = __expf(p[0][r] - m_run[r]); p[0][r] = p0;   // <= e^8, fp16-safe
                float p1 = __expf(p[1][r] - m_run[r]); p[1][r] = p1;
                l_run[r] += p0 + p1;
            }

            // P (C-layout) -> per-wave LDS -> A-layout fragment (k=32 local keys)
            unsigned short* Pw = Ps + wid * 512;
#pragma unroll
            for (int ni = 0; ni < 2; ni++)
#pragma unroll
                for (int r = 0; r < 4; r++) {
                    int q = g * 4 + r, kl = ni * 16 + fr;
                    Pw[q * 32 + (((kl >> 3) ^ (q & 3)) << 3) + (kl & 7)] = f2h(p[ni][r]);
                }
            f16x8 ap = *(const f16x8*)(Pw + fr * 32 + ((g ^ (fr & 3)) << 3));

            // O += P V (o-rescale already applied in branch above)
            __builtin_amdgcn_s_setprio(1);
#pragma unroll
            for (int nt = 0; nt < 16; nt++) {
                int dr = nt * 16 + fr;
                f16x8 bv = *(const f16x8*)(VC + dr * 64 + ((((c2 << 2) + g) ^ (dr & 7)) << 3));
                o[nt] = __builtin_amdgcn_mfma_f32_16x16x32_f16(ap, bv, o[nt], 0, 0, 0);
            }
            __builtin_amdgcn_s_setprio(0);
            __syncthreads();   // drains prefetch vmcnt; next iter reads other buffer
        }

        // reduce per-lane l over the 16 lanes of each row
#pragma unroll
        for (int r = 0; r < 4; r++) {
            float l = l_run[r];
#pragma unroll
            for (int sft = 1; sft < 16; sft <<= 1) l += __shfl_xor(l, sft);
            l_run[r] = l;
        }

        // flash-merge the two key-half waves (c2=0/1) per rowgroup, write output
        int mlbase = ((c2 * 4 + r2) * 4 + g) * 4;
        if (fr == 0) {
#pragma unroll
            for (int r = 0; r < 4; r++) {
                ML[(mlbase + r) * 2] = m_run[r];
                ML[(mlbase + r) * 2 + 1] = l_run[r];
            }
        }
        __syncthreads();
        int plbase = (((1 - c2) * 4 + r2) * 4 + g) * 4;
        float wS[4], linv[4];
#pragma unroll
        for (int r = 0; r < 4; r++) {
            float mp = ML[(plbase + r) * 2], lp = ML[(plbase + r) * 2 + 1];
            float ms = fmaxf(m_run[r], mp);
            wS[r] = __expf(m_run[r] - ms);
            float wp = __expf(mp - ms);
            linv[r] = __builtin_amdgcn_rcpf(l_run[r] * wS[r] + lp * wp);
        }
        float* Xl = X + (r2 * 64 + lane) * 68;
        if (c2 == 1) {
#pragma unroll
            for (int nt = 0; nt < 16; nt++)
#pragma unroll
                for (int r = 0; r < 4; r++) Xl[nt * 4 + r] = o[nt][r] * wS[r];
        }
        __syncthreads();
        if (c2 == 0) {
#pragma unroll
            for (int nt = 0; nt < 16; nt++)
#pragma unroll
                for (int r = 0; r < 4; r++) {
                    float val = (o[nt][r] * wS[r] + Xl[nt * 4 + r]) * linv[r];
                    int qr = q0 + g * 4 + r;
                    attn[(size_t)(b * 2048 + qr) * 2048 + n * 256 + nt * 16 + fr] = f2h(val);
                }
        }
        __syncthreads();   // protect LDS before next q-tile's STAGE
    }
}

extern "C" void kernel_launch(void* const* d_in, const int* in_sizes, int n_in,
                              void* d_out, int out_size, void* d_ws, size_t ws_size,
                              hipStream_t stream) {
    const float* x       = (const float*)d_in[0];
    // d_in[1] = attention_mask: deterministically causal -> applied analytically
    const float* Wq      = (const float*)d_in[2];
    const float* Wk      = (const float*)d_in[3];
    const float* Wv      = (const float*)d_in[4];
    const float* Wo      = (const float*)d_in[5];
    const float* q_scale = (const float*)d_in[6];
    const float* k_scale = (const float*)d_in[7];
    float* out = (float*)d_out;
    char* ws = (char*)d_ws;

    // workspace (peak 104 MB):
    //   [0,16M):   xh fp16 -> dead after GEMM1 -> Qh fp16 [16][2048][256]
    //   [16M,32M): WT fp16 (qkv weights B^T) -> dead after GEMM1 -> Kh[16,24M) Vt[24,32M)
    //   [32M,40M): WoT fp16
    //   [40M,104M): qkv f32 4096x4096 -> dead after V-transpose -> attnb fp16 [40,56M)
    const size_t MB = 1024 * 1024;
    unsigned short* xh    = (unsigned short*)ws;
    unsigned short* Qh    = (unsigned short*)ws;
    unsigned short* WT    = (unsigned short*)(ws + 16 * MB);
    unsigned short* Kh    = (unsigned short*)(ws + 16 * MB);
    unsigned short* Vt    = (unsigned short*)(ws + 24 * MB);
    unsigned short* WoT   = (unsigned short*)(ws + 32 * MB);
    float*          qkv   = (float*)(ws + 40 * MB);
    unsigned short* attnb = (unsigned short*)(ws + 40 * MB);

    dim3 tb(32, 8);
    k_cvt<<<dim3(8192), dim3(256), 0, stream>>>(x, xh, 2097152);
    k_transpose_cvt<<<dim3(8, 64, 8), tb, 0, stream>>>(Wq, WT, 256, 2048, 524288L, 524288L);
    k_transpose_cvt<<<dim3(8, 64, 4), tb, 0, stream>>>(Wk, WT + (size_t)2048 * 2048, 256, 2048, 524288L, 524288L);
    k_transpose_cvt<<<dim3(8, 64, 4), tb, 0, stream>>>(Wv, WT + (size_t)3072 * 2048, 256, 2048, 524288L, 524288L);

    k_gemm256<<<dim3(256), dim3(512), 0, stream>>>(xh, WT, qkv, 4096, 4096, 2048, 16);
    k_norm_rope<<<dim3(65536), dim3(256), 0, stream>>>(qkv, q_scale, k_scale, Qh, Kh);
    for (int b = 0; b < 2; b++)
        k_transpose_cvt<<<dim3(8, 64, 4), tb, 0, stream>>>(qkv + (size_t)b * 2048 * 4096 + 3072,
                                                           Vt + (size_t)b * 4 * 256 * 2048,
                                                           4096, 2048, 256L, 524288L);
    k_attn<<<dim3(256), dim3(512), 0, stream>>>(Qh, Kh, Vt, attnb);

    k_transpose_cvt<<<dim3(64, 64, 1), tb, 0, stream>>>(Wo, WoT, 2048, 2048, 0L, 0L);
    k_gemm_f16<<<dim3(16, 32), dim3(256), 0, stream>>>(attnb, WoT, out, 4096, 2048, 2048);
}

// Round 8
// 274.947 us; speedup vs baseline: 2.4208x; 1.0015x over previous
//
#include <hip/hip_runtime.h>

#define AS1 __attribute__((address_space(1)))
#define AS3 __attribute__((address_space(3)))

typedef __attribute__((ext_vector_type(8))) _Float16 f16x8;
typedef __attribute__((ext_vector_type(4))) _Float16 f16x4;
typedef __attribute__((ext_vector_type(4))) float f32x4;

#define MFMA_K16(a, b, c) __builtin_amdgcn_mfma_f32_16x16x16f16(a, b, c, 0, 0, 0)

__device__ __forceinline__ unsigned short f2h(float f) {
    union { _Float16 h; unsigned short u; } v; v.h = (_Float16)f; return v.u;
}

__device__ __forceinline__ void gload16(const void* g, void* l) {
    __builtin_amdgcn_global_load_lds((const AS1 unsigned int*)g, (AS3 unsigned int*)l, 16, 0, 0);
}

#define GBAR() __builtin_amdgcn_s_barrier()
#define VM4()  asm volatile("s_waitcnt vmcnt(4)" ::: "memory")
#define VM0()  asm volatile("s_waitcnt vmcnt(0)" ::: "memory")

// ---------- f32 -> fp16 elementwise (x4 vectorized) ----------
__global__ __launch_bounds__(256) void k_cvt(const float* __restrict__ src,
                                             unsigned short* __restrict__ dst, int n4) {
    int i = blockIdx.x * 256 + threadIdx.x;
    if (i >= n4) return;
    float4 v = ((const float4*)src)[i];
    ushort4 o;
    o.x = f2h(v.x); o.y = f2h(v.y); o.z = f2h(v.z); o.w = f2h(v.w);
    ((ushort4*)dst)[i] = o;
}

// ---------- tiled transpose + convert: dst[c*ld_dst + r] = fp16(src[r*ld_src + c]) ----------
__global__ __launch_bounds__(256) void k_transpose_cvt(const float* __restrict__ src,
                                                       unsigned short* __restrict__ dst,
                                                       int ld_src, int ld_dst,
                                                       long zs_src, long zs_dst) {
    __shared__ float tile[32][33];
    long sb = (long)blockIdx.z * zs_src;
    long db = (long)blockIdx.z * zs_dst;
    int c0 = blockIdx.x * 32, r0 = blockIdx.y * 32;
    int tx = threadIdx.x, ty = threadIdx.y;
#pragma unroll
    for (int i = 0; i < 4; i++)
        tile[ty + i * 8][tx] = src[sb + (long)(r0 + ty + i * 8) * ld_src + c0 + tx];
    __syncthreads();
#pragma unroll
    for (int i = 0; i < 4; i++)
        dst[db + (long)(c0 + ty + i * 8) * ld_dst + r0 + tx] = f2h(tile[tx][ty + i * 8]);
}

// ======== 256x256 8-phase fp16 GEMM (T2+T3+T4+T5): C = A(MxK) * Bt(NxK)^T, f32 out ========
template<int BUF, int MIH>
__device__ __forceinline__ void rdA(const unsigned short* SA, int wm, int fr, int g,
                                    f16x8 (&af)[4][2]) {
#pragma unroll
    for (int m = 0; m < 4; m++)
#pragma unroll
        for (int kk = 0; kk < 2; kk++) {
            int pos = wm * 64 + m * 16 + fr;
            af[m][kk] = *(const f16x8*)(SA + BUF * 16384 + MIH * 8192 + pos * 64 +
                                        (((kk * 4 + g) ^ (fr & 7)) << 3));
        }
}

template<int BUF, int NIH>
__device__ __forceinline__ void rdB(const unsigned short* SB, int wn, int fr, int g,
                                    f16x8 (&bf)[2][2]) {
#pragma unroll
    for (int ni2 = 0; ni2 < 2; ni2++)
#pragma unroll
        for (int kk = 0; kk < 2; kk++) {
            int pos = wn * 32 + ni2 * 16 + fr;
            bf[ni2][kk] = *(const f16x8*)(SB + BUF * 16384 + NIH * 8192 + pos * 64 +
                                          (((kk * 4 + g) ^ (fr & 7)) << 3));
        }
}

template<int MIH, int NIH>
__device__ __forceinline__ void mm16(f16x8 (&af)[4][2], f16x8 (&bf)[2][2], f32x4 (&acc)[8][4]) {
    __builtin_amdgcn_s_setprio(1);
#pragma unroll
    for (int m = 0; m < 4; m++)
#pragma unroll
        for (int ni2 = 0; ni2 < 2; ni2++)
#pragma unroll
            for (int kk = 0; kk < 2; kk++)
                acc[MIH * 4 + m][NIH * 2 + ni2] = __builtin_amdgcn_mfma_f32_16x16x32_f16(
                    af[m][kk], bf[ni2][kk], acc[MIH * 4 + m][NIH * 2 + ni2], 0, 0, 0);
    __builtin_amdgcn_s_setprio(0);
}

__global__ __launch_bounds__(512, 1) void k_gemm256(const unsigned short* __restrict__ A,
                                                    const unsigned short* __restrict__ Bt,
                                                    float* __restrict__ C,
                                                    int M, int N, int K, int nbx) {
    __shared__ __align__(16) unsigned short sm[65536];   // 128 KB
    unsigned short* SA = sm;
    unsigned short* SB = sm + 32768;

    int tid = threadIdx.x, lane = tid & 63, wid = tid >> 6;
    int g = lane >> 4, fr = lane & 15;
    int wm = wid >> 2, wn = wid & 3;

    int bid = blockIdx.x;
    int sid = (bid & 7) * ((int)gridDim.x >> 3) + (bid >> 3);
    int by = sid / nbx, bx = sid % nbx;
    int rowA0 = by * 256, colB0 = bx * 256;

    f32x4 acc[8][4];
#pragma unroll
    for (int mi = 0; mi < 8; mi++)
#pragma unroll
        for (int ni = 0; ni < 4; ni++) acc[mi][ni] = (f32x4){0.f, 0.f, 0.f, 0.f};

    auto stA = [&](int buf, int h, int kt) {
#pragma unroll
        for (int t = 0; t < 2; t++) {
            int i = t * 512 + tid;
            int pos = i >> 3;
            int grow = rowA0 + ((pos >> 6) << 7) + h * 64 + (pos & 63);
            int cg = (i & 7) ^ (pos & 7);
            gload16(A + (size_t)grow * K + kt * 64 + cg * 8,
                    SA + buf * 16384 + h * 8192 + pos * 64 + (i & 7) * 8);
        }
    };
    auto stB = [&](int buf, int h, int kt) {
#pragma unroll
        for (int t = 0; t < 2; t++) {
            int i = t * 512 + tid;
            int pos = i >> 3;
            int gcol = colB0 + ((pos >> 5) << 6) + h * 32 + (pos & 31);
            int cg = (i & 7) ^ (pos & 7);
            gload16(Bt + (size_t)gcol * K + kt * 64 + cg * 8,
                    SB + buf * 16384 + h * 8192 + pos * 64 + (i & 7) * 8);
        }
    };

    int nT = K >> 6;
    stA(0, 0, 0); stB(0, 0, 0); stA(0, 1, 0); stB(0, 1, 0);
    stA(1, 0, 1); stB(1, 0, 1);
    VM4();
    GBAR();

    f16x8 af[4][2], bf[2][2];
    int nIt = nT >> 1;
    for (int it = 0; it < nIt; it++) {
        int T = it * 2;
        bool s36 = (T + 2 < nT), s78 = (T + 3 < nT);
        rdA<0, 0>(SA, wm, fr, g, af); rdB<0, 0>(SB, wn, fr, g, bf);
        stA(1, 1, T + 1);
        GBAR(); mm16<0, 0>(af, bf, acc); GBAR();
        rdB<0, 1>(SB, wn, fr, g, bf);
        stB(1, 1, T + 1);
        GBAR(); mm16<0, 1>(af, bf, acc); GBAR();
        rdA<0, 1>(SA, wm, fr, g, af); rdB<0, 0>(SB, wn, fr, g, bf);
        if (s36) stA(0, 0, T + 2);
        GBAR(); mm16<1, 0>(af, bf, acc); GBAR();
        rdB<0, 1>(SB, wn, fr, g, bf);
        if (s36) { stB(0, 0, T + 2); VM4(); } else { VM0(); }
        GBAR(); mm16<1, 1>(af, bf, acc); GBAR();
        rdA<1, 0>(SA, wm, fr, g, af); rdB<1, 0>(SB, wn, fr, g, bf);
        if (s36) stA(0, 1, T + 2);
        GBAR(); mm16<0, 0>(af, bf, acc); GBAR();
        rdB<1, 1>(SB, wn, fr, g, bf);
        if (s36) stB(0, 1, T + 2);
        GBAR(); mm16<0, 1>(af, bf, acc); GBAR();
        rdA<1, 1>(SA, wm, fr, g, af); rdB<1, 0>(SB, wn, fr, g, bf);
        if (s78) stA(1, 0, T + 3);
        GBAR(); mm16<1, 0>(af, bf, acc); GBAR();
        rdB<1, 1>(SB, wn, fr, g, bf);
        if (s78) { stB(1, 0, T + 3); VM4(); } else { VM0(); }
        GBAR(); mm16<1, 1>(af, bf, acc); GBAR();
    }

#pragma unroll
    for (int mi = 0; mi < 8; mi++) {
        int row = rowA0 + wm * 128 + mi * 16 + g * 4;
#pragma unroll
        for (int ni = 0; ni < 4; ni++) {
            int col = colB0 + wn * 64 + ni * 16 + fr;
#pragma unroll
            for (int r = 0; r < 4; r++)
                C[(size_t)(row + r) * N + col] = acc[mi][ni][r];
        }
    }
}

// ---------- fp16 GEMM (out-proj): C = A(MxK) * Bt(NxK)^T, f32 out. 128x128 tile ----------
__global__ __launch_bounds__(256) void k_gemm_f16(const unsigned short* __restrict__ A,
                                                  const unsigned short* __restrict__ Bt,
                                                  float* __restrict__ C,
                                                  int M, int N, int K) {
    __shared__ unsigned short As[128 * 64];
    __shared__ unsigned short Bs[128 * 64];
    int tid = threadIdx.x;
    int lane = tid & 63, wid = tid >> 6;
    int g = lane >> 4, fr = lane & 15;
    int rowA0 = blockIdx.y * 128;
    int colB0 = blockIdx.x * 128;

    f32x4 zero = {0.f, 0.f, 0.f, 0.f};
    f32x4 acc[4][4];
#pragma unroll
    for (int mi = 0; mi < 4; mi++)
#pragma unroll
        for (int ni = 0; ni < 4; ni++) acc[mi][ni] = zero;

    const unsigned short* ag[4];
    const unsigned short* bg[4];
#pragma unroll
    for (int j = 0; j < 4; j++) {
        int id = j * 256 + tid;
        int r = id >> 3;
        int c = (id & 7) ^ (r & 7);
        ag[j] = A + (size_t)(rowA0 + r) * K + c * 8;
        bg[j] = Bt + (size_t)(colB0 + r) * K + c * 8;
    }

    int nK = K >> 6;
    for (int kt = 0; kt < nK; kt++) {
#pragma unroll
        for (int j = 0; j < 4; j++) {
            int id = j * 256 + tid;
            gload16(ag[j], As + id * 8);
            gload16(bg[j], Bs + id * 8);
            ag[j] += 64; bg[j] += 64;
        }
        __syncthreads();
#pragma unroll
        for (int kk = 0; kk < 2; kk++) {
            f16x8 af[4], bfr[4];
#pragma unroll
            for (int mi = 0; mi < 4; mi++) {
                int r = (wid >> 1) * 64 + mi * 16 + fr;
                af[mi] = *(const f16x8*)(As + r * 64 + ((((kk << 2) + g) ^ (r & 7)) << 3));
            }
#pragma unroll
            for (int ni = 0; ni < 4; ni++) {
                int r = (wid & 1) * 64 + ni * 16 + fr;
                bfr[ni] = *(const f16x8*)(Bs + r * 64 + ((((kk << 2) + g) ^ (r & 7)) << 3));
            }
#pragma unroll
            for (int mi = 0; mi < 4; mi++)
#pragma unroll
                for (int ni = 0; ni < 4; ni++)
                    acc[mi][ni] = __builtin_amdgcn_mfma_f32_16x16x32_f16(af[mi], bfr[ni], acc[mi][ni], 0, 0, 0);
        }
        __syncthreads();
    }

#pragma unroll
    for (int mi = 0; mi < 4; mi++) {
        int row = rowA0 + (wid >> 1) * 64 + mi * 16 + g * 4;
#pragma unroll
        for (int ni = 0; ni < 4; ni++) {
            int col = colB0 + (wid & 1) * 64 + ni * 16 + fr;
#pragma unroll
            for (int r = 0; r < 4; r++)
                C[(size_t)(row + r) * N + col] = acc[mi][ni][r];
        }
    }
}

// ---------- RMS/L2 norm + partial RoPE; fp16 outputs ----------
__global__ __launch_bounds__(256) void k_norm_rope(float* __restrict__ qkv,
                                                   const float* __restrict__ q_scale,
                                                   const float* __restrict__ k_scale,
                                                   unsigned short* __restrict__ Qh,
                                                   unsigned short* __restrict__ Kh) {
    __shared__ float Y[256];
    __shared__ float red[4];
    int blk = blockIdx.x;
    int bt = blk >> 4, slot = blk & 15;
    int b = bt >> 11, t = bt & 2047;
    int h = threadIdx.x;
    int lane = h & 63, wid = h >> 6;

    float x = qkv[(size_t)bt * 4096 + slot * 256 + h];
    float v = x * x;
#pragma unroll
    for (int m = 1; m < 64; m <<= 1) v += __shfl_xor(v, m);
    if (lane == 0) red[wid] = v;
    __syncthreads();
    float ss = red[0] + red[1] + red[2] + red[3];

    float y;
    if (slot < 12) {
        float fac = rsqrtf(ss * (1.0f / 256.0f) + 1e-6f);
        const float* sc = (slot < 8) ? q_scale : k_scale;
        y = x * fac * (1.0f + sc[h]);
    } else {
        float fac = rsqrtf(ss + 1e-6f);
        y = x * fac;
    }
    Y[h] = y;
    __syncthreads();

    if (slot < 12) {
        float out;
        int hm = h & 127;
        if (hm < 64) {
            float inv = exp2f(-(float)hm * 0.10381025296522993f); // log2(10000)/128
            float fr = (float)t * inv;
            float s = sinf(fr), c = cosf(fr);
            float y1 = Y[hm], y2 = Y[128 + hm];
            out = (h < 128) ? (y1 * c - y2 * s) : (y2 * c + y1 * s);
        } else {
            out = y;
        }
        unsigned short hv = f2h(out);
        if (slot < 8)
            Qh[((size_t)(b * 8 + slot) * 2048 + t) * 256 + h] = hv;
        else
            Kh[((size_t)(b * 4 + (slot - 8)) * 2048 + t) * 256 + h] = hv;
    } else {
        qkv[(size_t)bt * 4096 + slot * 256 + h] = y;   // normalized v, f32 in-place
    }
}

// ---------- causal flash attention v5: swapped QK^T, in-register P, K=16 PV ----------
// grid 256 x 512 thr (8 waves). id = pair(4b)|npar(1b)|bkv(3b): id%8 = bkv -> XCD-affine.
// Waves: r2=wid&3 -> 16 q-rows, c2=wid>>2 -> 32-key half. S^T = mfma(K_frag, Q_frag):
// lane holds P[q=lane&15][keys {c2*32+t16*16+g*4+r}] -> softmax lane-local (2 shfl),
// P feeds PV directly as K=16 A-frags (zero LDS roundtrip). q-tiles {pair, 31-pair}.
__global__ __launch_bounds__(512, 2) void k_attn(const unsigned short* __restrict__ Qhg,
                                                 const unsigned short* __restrict__ Khg,
                                                 const unsigned short* __restrict__ Vtg,
                                                 unsigned short* __restrict__ attn) {
    __shared__ __align__(16) char smem[132096];
    unsigned short* Ks = (unsigned short*)smem;            // [2][64*256] fp16, chunk^=(key&7)
    unsigned short* Vs = (unsigned short*)(smem + 65536);  // [2][256*64] fp16, chunk^=(d&7)
    float* ML = (float*)(smem + 131072);                   // [2][4][16][2] (m,l)
    float* X = (float*)smem;                               // merge overlay [4][64][68] f32

    int id = blockIdx.x;
    int bkv = id & 7;
    int npar = (id >> 3) & 1;
    int pair = id >> 4;
    int b = bkv >> 2, kv = bkv & 3;
    int n = kv * 2 + npar;
    int bn = b * 8 + n;

    int tid = threadIdx.x, lane = tid & 63, wid = tid >> 6;
    int g = lane >> 4, fr = lane & 15;
    int r2 = wid & 3, c2 = wid >> 2;
    int g4 = g * 4;

    const unsigned short* Kh = Khg + (size_t)bkv * 2048 * 256;
    const unsigned short* Vh = Vtg + (size_t)bkv * 256 * 2048;
    const unsigned short* Qb = Qhg + (size_t)bn * 2048 * 256;

    // hoisted staging bases (fixed per thread; advance by kt)
    const unsigned short* kb[4];
    const unsigned short* vb[4];
    int sdst[4];
#pragma unroll
    for (int t2 = 0; t2 < 4; t2++) {
        int c_ = t2 * 512 + tid;
        int r = c_ >> 5, c = (c_ & 31) ^ (r & 7);
        kb[t2] = Kh + (size_t)r * 256 + c * 8;
        int d = c_ >> 3, cv = (c_ & 7) ^ (d & 7);
        vb[t2] = Vh + (size_t)d * 2048 + cv * 8;
        sdst[t2] = c_ * 8;
    }

    // K-read swizzle bases (kr & 7 == fr & 7 since c2*32, t16*16 are mult of 8)
    int krbase[2];
#pragma unroll
    for (int t16 = 0; t16 < 2; t16++) krbase[t16] = (c2 * 32 + t16 * 16 + fr) * 256;
    int s7 = fr & 7;
    // V-read slots constant per lane (d & 7 == fr & 7)
    int vslot[2];
#pragma unroll
    for (int t16 = 0; t16 < 2; t16++) vslot[t16] = (((c2 * 4 + t16 * 2 + (g >> 1)) ^ s7) << 3) + (g & 1) * 4;

    for (int half = 0; half < 2; half++) {
        int j = half ? 31 - pair : pair;
        int q0 = j * 64 + r2 * 16;

        const unsigned short* qrow = Qb + (size_t)(q0 + fr) * 256;
        f16x8 aq[8];
#pragma unroll
        for (int kk = 0; kk < 8; kk++) aq[kk] = *(const f16x8*)(qrow + kk * 32 + g * 8);

        f32x4 zero4 = {0.f, 0.f, 0.f, 0.f};
        f32x4 o[16];
#pragma unroll
        for (int i2 = 0; i2 < 16; i2++) o[i2] = zero4;
        float m_run = -1e30f;   // per-lane state for q = q0 + fr
        float l_run = 0.f;      // per-lane partial (reduced over g at merge)

        auto STAGE = [&](int bufi, int kt2) {
#pragma unroll
            for (int t2 = 0; t2 < 4; t2++) {
                gload16(kb[t2] + (size_t)kt2 * 16384, Ks + bufi * 16384 + sdst[t2]);
                gload16(vb[t2] + kt2 * 64, Vs + bufi * 16384 + sdst[t2]);
            }
        };

        STAGE(0, 0);
        __syncthreads();

        for (int kt = 0; kt <= j; kt++) {
            int cur = kt & 1;
            if (kt < j) STAGE(cur ^ 1, kt + 1);   // prefetch hides under compute

            const unsigned short* KH = Ks + cur * 16384;
            const unsigned short* VC = Vs + cur * 16384;
            int k0 = kt * 64;

            // S^T = K Q^T over this wave's 32 keys; 4 independent acc chains
            f32x4 se[2] = {zero4, zero4}, so2[2] = {zero4, zero4};
            __builtin_amdgcn_s_setprio(1);
#pragma unroll
            for (int kk = 0; kk < 8; kk += 2) {
#pragma unroll
                for (int t16 = 0; t16 < 2; t16++) {
                    f16x8 bk0 = *(const f16x8*)(KH + krbase[t16] + ((((kk << 2) + g) ^ s7) << 3));
                    f16x8 bk1 = *(const f16x8*)(KH + krbase[t16] + (((((kk + 1) << 2) + g) ^ s7) << 3));
                    se[t16] = __builtin_amdgcn_mfma_f32_16x16x32_f16(bk0, aq[kk], se[t16], 0, 0, 0);
                    so2[t16] = __builtin_amdgcn_mfma_f32_16x16x32_f16(bk1, aq[kk + 1], so2[t16], 0, 0, 0);
                }
            }
            __builtin_amdgcn_s_setprio(0);

            // softcap 50*tanh(s/50) = 50 - 100/(1+e^{0.04s}), causal mask; all lane-local
            int qg = q0 + fr;
            float pv[2][4];
            float ml = -1e30f;
#pragma unroll
            for (int t16 = 0; t16 < 2; t16++)
#pragma unroll
                for (int r = 0; r < 4; r++) {
                    float s = se[t16][r] + so2[t16][r];
                    float e = __expf(0.04f * s);
                    s = 50.f - 100.f * __builtin_amdgcn_rcpf(1.f + e);
                    int key = k0 + c2 * 32 + t16 * 16 + g4 + r;
                    if (key > qg) s = -1e9f;
                    pv[t16][r] = s;
                    ml = fmaxf(ml, s);
                }
            // row-max: in-lane done, reduce over the 4 g-lanes of this q
            ml = fmaxf(ml, __shfl_xor(ml, 16));
            ml = fmaxf(ml, __shfl_xor(ml, 32));

            // defer-max (THR=8)
            if (__any(ml > m_run + 8.f)) {
                float mnew = fmaxf(m_run, ml);
                float swl = __expf(m_run - mnew);
                m_run = mnew;
                l_run *= swl;
                float swr[4];
#pragma unroll
                for (int r = 0; r < 4; r++) swr[r] = __shfl(swl, g4 + r);  // factor for O-row g4+r
#pragma unroll
                for (int nt = 0; nt < 16; nt++)
#pragma unroll
                    for (int r = 0; r < 4; r++) o[nt][r] *= swr[r];
            }

            // P = exp(s - m_run), fp16 A-frags for K=16 PV (no data movement!)
            f16x4 pf[2];
#pragma unroll
            for (int t16 = 0; t16 < 2; t16++)
#pragma unroll
                for (int r = 0; r < 4; r++) {
                    float p = __expf(pv[t16][r] - m_run);
                    l_run += p;
                    pf[t16][r] = (_Float16)p;
                }

            // O += P V : per nt two K=16 MFMAs (keys t16*16+g4..+3 slice of V)
            __builtin_amdgcn_s_setprio(1);
#pragma unroll
            for (int nt = 0; nt < 16; nt++) {
                int dbase = (nt * 16 + fr) * 64;
                f16x4 bv0 = *(const f16x4*)(VC + dbase + vslot[0]);
                f16x4 bv1 = *(const f16x4*)(VC + dbase + vslot[1]);
                o[nt] = MFMA_K16(pf[0], bv0, o[nt]);
                o[nt] = MFMA_K16(pf[1], bv1, o[nt]);
            }
            __builtin_amdgcn_s_setprio(0);
            __syncthreads();   // drains prefetch vmcnt; next iter reads other buffer
        }

        // merge the two key-half waves (c2=0/1) per rowgroup
        float l2 = l_run + __shfl_xor(l_run, 16);
        l2 += __shfl_xor(l2, 32);
        if (lane < 16) {
            float* mlw = ML + ((c2 * 4 + r2) * 16 + lane) * 2;
            mlw[0] = m_run; mlw[1] = l2;
        }
        __syncthreads();
        float wO[4], li[4];
#pragma unroll
        for (int r = 0; r < 4; r++) {
            int qq = g4 + r;
            const float* p0 = ML + (r2 * 16 + qq) * 2;
            const float* p1 = ML + ((4 + r2) * 16 + qq) * 2;
            float m0 = p0[0], l0 = p0[1], m1 = p1[0], l1 = p1[1];
            float ms = fmaxf(m0, m1);
            float w0 = __expf(m0 - ms), w1 = __expf(m1 - ms);
            li[r] = __builtin_amdgcn_rcpf(fmaxf(l0 * w0 + l1 * w1, 1e-30f));
            wO[r] = c2 ? w1 : w0;
        }
        float* Xl = X + (r2 * 64 + lane) * 68;
        if (c2 == 1) {
#pragma unroll
            for (int nt = 0; nt < 16; nt++)
#pragma unroll
                for (int r = 0; r < 4; r++) Xl[nt * 4 + r] = o[nt][r] * wO[r];
        }
        __syncthreads();
        if (c2 == 0) {
#pragma unroll
            for (int nt = 0; nt < 16; nt++)
#pragma unroll
                for (int r = 0; r < 4; r++) {
                    float val = (o[nt][r] * wO[r] + Xl[nt * 4 + r]) * li[r];
                    int qr = q0 + g4 + r;
                    attn[(size_t)(b * 2048 + qr) * 2048 + n * 256 + nt * 16 + fr] = f2h(val);
                }
        }
        __syncthreads();   // protect LDS before next q-tile's STAGE
    }
}

extern "C" void kernel_launch(void* const* d_in, const int* in_sizes, int n_in,
                              void* d_out, int out_size, void* d_ws, size_t ws_size,
                              hipStream_t stream) {
    const float* x       = (const float*)d_in[0];
    // d_in[1] = attention_mask: deterministically causal -> applied analytically
    const float* Wq      = (const float*)d_in[2];
    const float* Wk      = (const float*)d_in[3];
    const float* Wv      = (const float*)d_in[4];
    const float* Wo      = (const float*)d_in[5];
    const float* q_scale = (const float*)d_in[6];
    const float* k_scale = (const float*)d_in[7];
    float* out = (float*)d_out;
    char* ws = (char*)d_ws;

    // workspace (peak 104 MB):
    //   [0,16M):   xh fp16 -> dead after GEMM1 -> Qh fp16 [16][2048][256]
    //   [16M,32M): WT fp16 (qkv weights B^T) -> dead after GEMM1 -> Kh[16,24M) Vt[24,32M)
    //   [32M,40M): WoT fp16
    //   [40M,104M): qkv f32 4096x4096 -> dead after V-transpose -> attnb fp16 [40,56M)
    const size_t MB = 1024 * 1024;
    unsigned short* xh    = (unsigned short*)ws;
    unsigned short* Qh    = (unsigned short*)ws;
    unsigned short* WT    = (unsigned short*)(ws + 16 * MB);
    unsigned short* Kh    = (unsigned short*)(ws + 16 * MB);
    unsigned short* Vt    = (unsigned short*)(ws + 24 * MB);
    unsigned short* WoT   = (unsigned short*)(ws + 32 * MB);
    float*          qkv   = (float*)(ws + 40 * MB);
    unsigned short* attnb = (unsigned short*)(ws + 40 * MB);

    dim3 tb(32, 8);
    k_cvt<<<dim3(8192), dim3(256), 0, stream>>>(x, xh, 2097152);
    k_transpose_cvt<<<dim3(8, 64, 8), tb, 0, stream>>>(Wq, WT, 256, 2048, 524288L, 524288L);
    k_transpose_cvt<<<dim3(8, 64, 4), tb, 0, stream>>>(Wk, WT + (size_t)2048 * 2048, 256, 2048, 524288L, 524288L);
    k_transpose_cvt<<<dim3(8, 64, 4), tb, 0, stream>>>(Wv, WT + (size_t)3072 * 2048, 256, 2048, 524288L, 524288L);

    k_gemm256<<<dim3(256), dim3(512), 0, stream>>>(xh, WT, qkv, 4096, 4096, 2048, 16);
    k_norm_rope<<<dim3(65536), dim3(256), 0, stream>>>(qkv, q_scale, k_scale, Qh, Kh);
    for (int b = 0; b < 2; b++)
        k_transpose_cvt<<<dim3(8, 64, 4), tb, 0, stream>>>(qkv + (size_t)b * 2048 * 4096 + 3072,
                                                           Vt + (size_t)b * 4 * 256 * 2048,
                                                           4096, 2048, 256L, 524288L);
    k_attn<<<dim3(256), dim3(512), 0, stream>>>(Qh, Kh, Vt, attnb);

    k_transpose_cvt<<<dim3(64, 64, 1), tb, 0, stream>>>(Wo, WoT, 2048, 2048, 0L, 0L);
    k_gemm_f16<<<dim3(16, 32), dim3(256), 0, stream>>>(attnb, WoT, out, 4096, 2048, 2048);
}